// Round 2
// baseline (232.685 us; speedup 1.0000x reference)
//
#include <hip/hip_runtime.h>

#define N 8192
#define KD 128
#define NCLS 10
#define GRID 512
#define TPB 256

typedef __attribute__((ext_vector_type(4))) int intx4;

// i8 fragment layout (K=64 per MFMA, two ks halves per K=128 row):
//   byte addr = idx16*2048 + ks*1024 + quad*256 + l16*16 + j   (k = ks*64+quad*16+j)
// Q holds rn(30*F) as i8; logit = (qa . qb) / 90.

__device__ __forceinline__ float slabmin(const int* __restrict__ Dpart, int slab) {
    float a = fminf(__int_as_float(Dpart[slab * 4 + 0]), __int_as_float(Dpart[slab * 4 + 1]));
    float b = fminf(__int_as_float(Dpart[slab * 4 + 2]), __int_as_float(Dpart[slab * 4 + 3]));
    return fminf(a, b);
}

// Device-scope grid barrier. Requires all GRID blocks co-resident
// (512 blocks = 2/CU x 256 CU, enforced via __launch_bounds__(256,2) + ~10KB LDS).
// Release: threadfence (buffer_wbl2) makes prior plain stores visible at the
// coherence point; acquire: threadfence (buffer_inv) drops stale L2 lines.
__device__ __forceinline__ void grid_barrier(int* bar, int target) {
    __syncthreads();
    if (threadIdx.x == 0) {
        __threadfence();
        __hip_atomic_fetch_add(bar, 1, __ATOMIC_ACQ_REL, __HIP_MEMORY_SCOPE_AGENT);
        while (__hip_atomic_load(bar, __ATOMIC_ACQUIRE, __HIP_MEMORY_SCOPE_AGENT) < target)
            __builtin_amdgcn_s_sleep(2);
        __threadfence();
    }
    __syncthreads();
}

__global__ __launch_bounds__(TPB, 2) void k_fused(const float* __restrict__ F,
                                                  const int* __restrict__ tgt,
                                                  float* __restrict__ diag10,
                                                  int* __restrict__ Q,
                                                  float* __restrict__ S,
                                                  int* __restrict__ cnt,
                                                  float* __restrict__ PS,
                                                  int* __restrict__ Dpart,
                                                  float* __restrict__ accg,
                                                  float* __restrict__ out) {
    const unsigned char* Qb = (const unsigned char*)Q;
    int b = blockIdx.x;
    int t = threadIdx.x;
    int* bar = cnt + 14;

    __shared__ int bmin;
    __shared__ union {
        struct { int lh[NCLS]; float red[2][NCLS][KD]; } cls;          // phase 1b
        struct { float Ss[NCLS * KD]; int cs[NCLS]; float wsum[4]; } fin; // phase 3
    } sh;

    // ================= Phase 1a: i8 convert, 16 rows per block =================
    {
        int row0 = b * 16;
        if (t == 0) bmin = 0x7f7fffff;       // +3.4e38 bits
        __syncthreads();
        if (t < 16)
            __hip_atomic_store(&PS[row0 + t], 0.f, __ATOMIC_RELAXED, __HIP_MEMORY_SCOPE_AGENT);
        int col4 = t & 31;   // which float4 of the row (k = col4*4)
        int rg = t >> 5;     // 0..7
#pragma unroll
        for (int sw = 0; sw < 2; ++sw) {
            int row = row0 + sw * 8 + rg;
            float4 v = *(const float4*)(F + (size_t)row * KD + col4 * 4);
            float sq = v.x * v.x + v.y * v.y + v.z * v.z + v.w * v.w;
#pragma unroll
            for (int off = 16; off >= 1; off >>= 1) sq += __shfl_xor(sq, off);
            if (col4 == 0) {
                float dg = 10.f * sq;
                diag10[row] = dg;
                atomicMin(&bmin, __float_as_int(dg));   // LDS atomic, 16/block
            }
            // i8 quantize: q = rn(30*clamp(v, +-4.2))
            int q0 = __float2int_rn(30.f * fminf(fmaxf(v.x, -4.2f), 4.2f));
            int q1 = __float2int_rn(30.f * fminf(fmaxf(v.y, -4.2f), 4.2f));
            int q2 = __float2int_rn(30.f * fminf(fmaxf(v.z, -4.2f), 4.2f));
            int q3 = __float2int_rn(30.f * fminf(fmaxf(v.w, -4.2f), 4.2f));
            int dq = (q0 & 255) | ((q1 & 255) << 8) | ((q2 & 255) << 16) | ((q3 & 255) << 24);
            int idx = (row >> 4) * 512 + (col4 >> 4) * 256 + ((col4 >> 2) & 3) * 64 +
                      (row & 15) * 4 + (col4 & 3);
            Q[idx] = dq;
        }
        __syncthreads();
        if (t == 0) Dpart[b] = bmin;         // plain store; fenced at barrier
    }

    // ================= Phase 1b: class sums (blocks 0..127, 64 rows each) ======
    if (b < 128) {
        int row0 = b * 64;
        int k = t & 127, h = t >> 7;
        if (t < NCLS) sh.cls.lh[t] = 0;
        __syncthreads();
        if (t < 64) atomicAdd(&sh.cls.lh[tgt[row0 + t]], 1);
        float local[NCLS];
#pragma unroll
        for (int c = 0; c < NCLS; ++c) local[c] = 0.f;
        for (int ii = 0; ii < 32; ++ii) {
            int row = row0 + h * 32 + ii;
            float v = F[(size_t)row * KD + k];
            int c = tgt[row];
#pragma unroll
            for (int cc = 0; cc < NCLS; ++cc) local[cc] += (cc == c) ? v : 0.f;
        }
#pragma unroll
        for (int cc = 0; cc < NCLS; ++cc) sh.cls.red[h][cc][k] = local[cc];
        __syncthreads();
        if (h == 0) {
#pragma unroll
            for (int cc = 0; cc < NCLS; ++cc)
                atomicAdd(&S[cc * KD + k], sh.cls.red[0][cc][k] + sh.cls.red[1][cc][k]);
            if (t < NCLS) atomicAdd(&cnt[t], sh.cls.lh[t]);
        }
    }

    grid_barrier(bar, GRID);

    // ================= Phase 2: symmetric-half i8 MFMA pair sweep ==============
    {
        int bx = b & 127, y = b >> 7;
        int w = t >> 6, lane = t & 63;
        int quad = lane >> 4, l16 = lane & 15;
        int row0 = bx * 64;

        float dmr = slabmin(Dpart, bx);   // row-slab min diag

        // A fragments: af[it][ks] for rows row0 + it*16 + l16
        intx4 af[4][2];
#pragma unroll
        for (int it = 0; it < 4; ++it)
#pragma unroll
            for (int ks = 0; ks < 2; ++ks)
                af[it][ks] =
                    *(const intx4*)(Qb + (size_t)(bx * 4 + it) * 2048 + ks * 1024 + lane * 16);

        bool ext = (y == 0) && (bx < 64) && (w == 0);   // handles the dd=64 tile

        // double-buffered B fragments
        intx4 bufs[2][4][2];
        {   // prologue: load step 0 (dd = y*16 + w)
            int col0 = ((bx + y * 16 + w) & 127) * 64;
            const unsigned char* bp = Qb + (size_t)(col0 >> 4) * 2048 + lane * 16;
#pragma unroll
            for (int tj = 0; tj < 4; ++tj)
#pragma unroll
                for (int ks = 0; ks < 2; ++ks)
                    bufs[0][tj][ks] = *(const intx4*)(bp + tj * 2048 + ks * 1024);
        }

#pragma unroll
        for (int s = 0; s < 4; ++s) {
            // prefetch next tile (step s+1, or the dd=64 extra tile on the last step)
            if (s < 3) {
                int coln = ((bx + y * 16 + (s + 1) * 4 + w) & 127) * 64;
                const unsigned char* bp = Qb + (size_t)(coln >> 4) * 2048 + lane * 16;
#pragma unroll
                for (int tj = 0; tj < 4; ++tj)
#pragma unroll
                    for (int ks = 0; ks < 2; ++ks)
                        bufs[(s + 1) & 1][tj][ks] = *(const intx4*)(bp + tj * 2048 + ks * 1024);
            } else if (ext) {
                int coln = (bx + 64) * 64;
                const unsigned char* bp = Qb + (size_t)(coln >> 4) * 2048 + lane * 16;
#pragma unroll
                for (int tj = 0; tj < 4; ++tj)
#pragma unroll
                    for (int ks = 0; ks < 2; ++ks)
                        bufs[0][tj][ks] = *(const intx4*)(bp + tj * 2048 + ks * 1024);
            }

            int csb = (bx + y * 16 + s * 4 + w) & 127;   // col slab index
            int col0 = csb * 64;
            int thrq = (int)((fminf(dmr, slabmin(Dpart, csb)) - 60.f) * 90.f);

            intx4 acc[4][4];
#pragma unroll
            for (int it = 0; it < 4; ++it)
#pragma unroll
                for (int tj = 0; tj < 4; ++tj)
                    acc[it][tj] = (intx4){0, 0, 0, 0};
#pragma unroll
            for (int ks = 0; ks < 2; ++ks)
#pragma unroll
                for (int it = 0; it < 4; ++it)
#pragma unroll
                    for (int tj = 0; tj < 4; ++tj)
                        acc[it][tj] = __builtin_amdgcn_mfma_i32_16x16x64_i8(
                            af[it][ks], bufs[s & 1][tj][ks], acc[it][tj], 0, 0, 0);

            int mx = -2147483647;
#pragma unroll
            for (int it = 0; it < 4; ++it)
#pragma unroll
                for (int tj = 0; tj < 4; ++tj) {
                    int a01 = max(acc[it][tj][0], acc[it][tj][1]);
                    int a23 = max(acc[it][tj][2], acc[it][tj][3]);
                    mx = max(mx, max(a01, a23));
                }

            if (__any(mx > thrq)) {
                bool has_diag = (col0 == row0);   // wave-uniform (dd==0)
                // row side: exp(l - M_row) into PS[row] (self excluded on diag tile)
#pragma unroll
                for (int it = 0; it < 4; ++it)
#pragma unroll
                    for (int r = 0; r < 4; ++r) {
                        int grow = row0 + it * 16 + quad * 4 + r;
                        float Mrow = diag10[grow];
                        float rs = 0.f;
#pragma unroll
                        for (int tj = 0; tj < 4; ++tj) {
                            int gcol = col0 + tj * 16 + l16;
                            float lv = (float)acc[it][tj][r] * (1.f / 90.f);
                            float ev = __expf(lv - Mrow);
                            rs += (grow == gcol) ? 0.f : ev;
                        }
                        rs += __shfl_xor(rs, 1, 16);
                        rs += __shfl_xor(rs, 2, 16);
                        rs += __shfl_xor(rs, 4, 16);
                        rs += __shfl_xor(rs, 8, 16);
                        if (l16 == 0) atomicAdd(&PS[grow], rs);
                    }
                // col side (off-diag tiles only): exp(l - M_col) into PS[col]
                if (!has_diag) {
#pragma unroll
                    for (int tj = 0; tj < 4; ++tj) {
                        int gcol = col0 + tj * 16 + l16;
                        float Mcol = diag10[gcol];
                        float cs_ = 0.f;
#pragma unroll
                        for (int it = 0; it < 4; ++it)
#pragma unroll
                            for (int r = 0; r < 4; ++r)
                                cs_ += __expf((float)acc[it][tj][r] * (1.f / 90.f) - Mcol);
                        cs_ += __shfl_xor(cs_, 16);
                        cs_ += __shfl_xor(cs_, 32);
                        if (quad == 0) atomicAdd(&PS[gcol], cs_);
                    }
                }
            }
        }

        // dd=64 extra tile (unordered pair {bx, bx+64}), off-diag semantics
        if (ext) {
            int col0 = (bx + 64) * 64;
            int thrq = (int)((fminf(dmr, slabmin(Dpart, bx + 64)) - 60.f) * 90.f);
            intx4 acc[4][4];
#pragma unroll
            for (int it = 0; it < 4; ++it)
#pragma unroll
                for (int tj = 0; tj < 4; ++tj)
                    acc[it][tj] = (intx4){0, 0, 0, 0};
#pragma unroll
            for (int ks = 0; ks < 2; ++ks)
#pragma unroll
                for (int it = 0; it < 4; ++it)
#pragma unroll
                    for (int tj = 0; tj < 4; ++tj)
                        acc[it][tj] = __builtin_amdgcn_mfma_i32_16x16x64_i8(
                            af[it][ks], bufs[0][tj][ks], acc[it][tj], 0, 0, 0);

            int mx = -2147483647;
#pragma unroll
            for (int it = 0; it < 4; ++it)
#pragma unroll
                for (int tj = 0; tj < 4; ++tj) {
                    int a01 = max(acc[it][tj][0], acc[it][tj][1]);
                    int a23 = max(acc[it][tj][2], acc[it][tj][3]);
                    mx = max(mx, max(a01, a23));
                }
            if (__any(mx > thrq)) {
#pragma unroll
                for (int it = 0; it < 4; ++it)
#pragma unroll
                    for (int r = 0; r < 4; ++r) {
                        int grow = row0 + it * 16 + quad * 4 + r;
                        float Mrow = diag10[grow];
                        float rs = 0.f;
#pragma unroll
                        for (int tj = 0; tj < 4; ++tj) {
                            float lv = (float)acc[it][tj][r] * (1.f / 90.f);
                            rs += __expf(lv - Mrow);
                        }
                        rs += __shfl_xor(rs, 1, 16);
                        rs += __shfl_xor(rs, 2, 16);
                        rs += __shfl_xor(rs, 4, 16);
                        rs += __shfl_xor(rs, 8, 16);
                        if (l16 == 0) atomicAdd(&PS[grow], rs);
                    }
#pragma unroll
                for (int tj = 0; tj < 4; ++tj) {
                    int gcol = col0 + tj * 16 + l16;
                    float Mcol = diag10[gcol];
                    float cs_ = 0.f;
#pragma unroll
                    for (int it = 0; it < 4; ++it)
#pragma unroll
                        for (int r = 0; r < 4; ++r)
                            cs_ += __expf((float)acc[it][tj][r] * (1.f / 90.f) - Mcol);
                    cs_ += __shfl_xor(cs_, 16);
                    cs_ += __shfl_xor(cs_, 32);
                    if (quad == 0) atomicAdd(&PS[gcol], cs_);
                }
            }
        }
    }

    grid_barrier(bar, 2 * GRID);

    // ================= Phase 3: posdot + log-term + reduce (blocks 0..127) =====
    if (b >= 128) return;
    {
        for (int i = t; i < NCLS * KD; i += TPB) sh.fin.Ss[i] = S[i];
        if (t < NCLS) sh.fin.cs[t] = cnt[t];
        __syncthreads();

        int g = t >> 2, q = t & 3;            // 4 lanes per row
        int row = b * 64 + g;
        int c = tgt[row];
        float dot = 0.f;
#pragma unroll
        for (int i = 0; i < 8; ++i) {
            float4 f = *(const float4*)(F + (size_t)row * KD + i * 16 + q * 4);
            float4 s = *(const float4*)(sh.fin.Ss + c * KD + i * 16 + q * 4);
            dot += f.x * s.x + f.y * s.y + f.z * s.z + f.w * s.w;
        }
        dot += __shfl_xor(dot, 1, 4);
        dot += __shfl_xor(dot, 2, 4);

        float mlp = 0.f;
        if (q == 0) {
            float M = diag10[row];
            float pp = 10.f * dot - M;            // sum over positives of logits
            float T = PS[row];                    // surviving shifted exp mass
            float np = (float)(sh.fin.cs[c] - 1);
            mlp = (np < 0.5f) ? 0.f : (pp - np * (M + __logf(T + 1e-20f))) / np;
        }
#pragma unroll
        for (int off = 32; off >= 1; off >>= 1) mlp += __shfl_xor(mlp, off);
        int lane = t & 63, w = t >> 6;
        if (lane == 0) sh.fin.wsum[w] = mlp;
        __syncthreads();
        if (t == 0) {
            atomicAdd(accg, (sh.fin.wsum[0] + sh.fin.wsum[1]) + (sh.fin.wsum[2] + sh.fin.wsum[3]));
            __threadfence();
            int old = atomicAdd(&cnt[12], 1);   // ticket among 128 final blocks
            if (old == 127) {
                float tot = atomicAdd(accg, 0.0f);   // coherent read of total
                double sp = 0.0, sn = 0.0;
                for (int cc = 0; cc < NCLS; ++cc) {
                    double n = (double)sh.fin.cs[cc];
                    sp += n * (n - 1.0);
                    sn += n * ((double)N - n);
                }
                out[0] = (float)(-(0.1 / 0.07) * ((double)tot / (double)N));
                out[1] = (float)(sp / (double)N);
                out[2] = (float)(sn / (double)N);
            }
        }
    }
}

extern "C" void kernel_launch(void* const* d_in, const int* in_sizes, int n_in,
                              void* d_out, int out_size, void* d_ws, size_t ws_size,
                              hipStream_t stream) {
    const float* F = (const float*)d_in[0];
    const int* tgt = (const int*)d_in[1];
    float* out = (float*)d_out;
    char* ws = (char*)d_ws;

    int* cnt = (int*)(ws);                       // 64 B (ticket at cnt[12], barrier at cnt[14])
    float* acc = (float*)(ws + 64);              // 4 B
    float* S = (float*)(ws + 128);               // 5120 B -> ends 5248
    float* PS = (float*)(ws + 8192);             // 32 KiB (zeroed in phase 1)
    int* Dpart = (int*)(ws + 49152);             // 2 KiB (per-16-row diag mins)
    float* diag10 = (float*)(ws + 65536);        // 32 KiB
    int* Q = (int*)(ws + (1u << 20));            // 1 MiB (i8 frags of 30*F)

    hipMemsetAsync(ws, 0, 8192, stream);         // cnt + acc + S (+ barrier counter)
    k_fused<<<GRID, TPB, 0, stream>>>(F, tgt, diag10, Q, S, cnt, PS, Dpart, acc, out);
}

// Round 4
// 164.125 us; speedup vs baseline: 1.4177x; 1.4177x over previous
//
#include <hip/hip_runtime.h>

#define N 8192
#define KD 128
#define NCLS 10
#define GRID 512
#define TPB 256

typedef __attribute__((ext_vector_type(4))) int intx4;

// i8 fragment layout (K=64 per MFMA, two ks halves per K=128 row):
//   byte addr = idx16*2048 + ks*1024 + quad*256 + l16*16 + j   (k = ks*64+quad*16+j)
// Q holds rn(30*F) as i8; logit = (qa . qb) / 90.

__device__ __forceinline__ float slabmin(const int* __restrict__ Dpart, int slab) {
    float a = fminf(__int_as_float(Dpart[slab * 4 + 0]), __int_as_float(Dpart[slab * 4 + 1]));
    float b = fminf(__int_as_float(Dpart[slab * 4 + 2]), __int_as_float(Dpart[slab * 4 + 3]));
    return fminf(a, b);
}

// Device-scope grid barrier, RELAXED polling.
// r2 lesson: ACQUIRE polls emit a cache-invalidate per iteration; ~500 spinners
// storm the L2s with invalidates and stall the still-working blocks. Poll RELAXED
// (agent-scope atomicity still guarantees visibility), then ONE acquire fence.
__device__ __forceinline__ void grid_barrier(int* bar, int target) {
    __syncthreads();
    if (threadIdx.x == 0) {
        __threadfence();   // release: make this block's prior stores visible
        __hip_atomic_fetch_add(bar, 1, __ATOMIC_RELAXED, __HIP_MEMORY_SCOPE_AGENT);
        while (__hip_atomic_load(bar, __ATOMIC_RELAXED, __HIP_MEMORY_SCOPE_AGENT) < target)
            __builtin_amdgcn_s_sleep(4);
        __threadfence();   // acquire: drop stale lines before reading peers' data
    }
    __syncthreads();
}

__global__ __launch_bounds__(TPB, 2) void k_fused(const float* __restrict__ F,
                                                  const int* __restrict__ tgt,
                                                  float* __restrict__ diag10,
                                                  int* __restrict__ Q,
                                                  float* __restrict__ S,
                                                  int* __restrict__ cnt,
                                                  float* __restrict__ PS,
                                                  int* __restrict__ Dpart,
                                                  float* __restrict__ accg,
                                                  int* __restrict__ bar,
                                                  float* __restrict__ out) {
    const unsigned char* Qb = (const unsigned char*)Q;
    int b = blockIdx.x;
    int t = threadIdx.x;

    __shared__ int bmin;
    __shared__ union {
        struct { int lh[NCLS]; float red[2][NCLS][KD]; } cls;          // phase 1b
        struct { float Ss[NCLS * KD]; int cs[NCLS]; float wsum[4]; } fin; // phase 3
    } sh;

    // ================= Phase 1a: i8 convert, 16 rows per block =================
    {
        int row0 = b * 16;
        if (t == 0) bmin = 0x7f7fffff;       // +3.4e38 bits
        __syncthreads();
        if (t < 16)
            __hip_atomic_store(&PS[row0 + t], 0.f, __ATOMIC_RELAXED, __HIP_MEMORY_SCOPE_AGENT);
        int col4 = t & 31;   // which float4 of the row (k = col4*4)
        int rg = t >> 5;     // 0..7
#pragma unroll
        for (int sw = 0; sw < 2; ++sw) {
            int row = row0 + sw * 8 + rg;
            float4 v = *(const float4*)(F + (size_t)row * KD + col4 * 4);
            float sq = v.x * v.x + v.y * v.y + v.z * v.z + v.w * v.w;
#pragma unroll
            for (int off = 16; off >= 1; off >>= 1) sq += __shfl_xor(sq, off);
            if (col4 == 0) {
                float dg = 10.f * sq;
                diag10[row] = dg;
                atomicMin(&bmin, __float_as_int(dg));   // LDS atomic, 16/block
            }
            // i8 quantize: q = rn(30*clamp(v, +-4.2))
            int q0 = __float2int_rn(30.f * fminf(fmaxf(v.x, -4.2f), 4.2f));
            int q1 = __float2int_rn(30.f * fminf(fmaxf(v.y, -4.2f), 4.2f));
            int q2 = __float2int_rn(30.f * fminf(fmaxf(v.z, -4.2f), 4.2f));
            int q3 = __float2int_rn(30.f * fminf(fmaxf(v.w, -4.2f), 4.2f));
            int dq = (q0 & 255) | ((q1 & 255) << 8) | ((q2 & 255) << 16) | ((q3 & 255) << 24);
            int idx = (row >> 4) * 512 + (col4 >> 4) * 256 + ((col4 >> 2) & 3) * 64 +
                      (row & 15) * 4 + (col4 & 3);
            Q[idx] = dq;
        }
        __syncthreads();
        if (t == 0) Dpart[b] = bmin;         // plain store; fenced at barrier
    }

    // ================= Phase 1b: class sums (blocks 0..127, 64 rows each) ======
    if (b < 128) {
        int row0 = b * 64;
        int k = t & 127, h = t >> 7;
        if (t < NCLS) sh.cls.lh[t] = 0;
        __syncthreads();
        if (t < 64) atomicAdd(&sh.cls.lh[tgt[row0 + t]], 1);
        float local[NCLS];
#pragma unroll
        for (int c = 0; c < NCLS; ++c) local[c] = 0.f;
        for (int ii = 0; ii < 32; ++ii) {
            int row = row0 + h * 32 + ii;
            float v = F[(size_t)row * KD + k];
            int c = tgt[row];
#pragma unroll
            for (int cc = 0; cc < NCLS; ++cc) local[cc] += (cc == c) ? v : 0.f;
        }
#pragma unroll
        for (int cc = 0; cc < NCLS; ++cc) sh.cls.red[h][cc][k] = local[cc];
        __syncthreads();
        if (h == 0) {
#pragma unroll
            for (int cc = 0; cc < NCLS; ++cc)
                atomicAdd(&S[cc * KD + k], sh.cls.red[0][cc][k] + sh.cls.red[1][cc][k]);
            if (t < NCLS) atomicAdd(&cnt[t], sh.cls.lh[t]);
        }
    }

    grid_barrier(bar, GRID);

    // ================= Phase 2: symmetric-half i8 MFMA pair sweep ==============
    {
        int bx = b & 127, y = b >> 7;
        int w = t >> 6, lane = t & 63;
        int quad = lane >> 4, l16 = lane & 15;
        int row0 = bx * 64;

        float dmr = slabmin(Dpart, bx);   // row-slab min diag

        // A fragments: af[it][ks] for rows row0 + it*16 + l16
        intx4 af[4][2];
#pragma unroll
        for (int it = 0; it < 4; ++it)
#pragma unroll
            for (int ks = 0; ks < 2; ++ks)
                af[it][ks] =
                    *(const intx4*)(Qb + (size_t)(bx * 4 + it) * 2048 + ks * 1024 + lane * 16);

        bool ext = (y == 0) && (bx < 64) && (w == 0);   // handles the dd=64 tile

        // double-buffered B fragments
        intx4 bufs[2][4][2];
        {   // prologue: load step 0 (dd = y*16 + w)
            int col0 = ((bx + y * 16 + w) & 127) * 64;
            const unsigned char* bp = Qb + (size_t)(col0 >> 4) * 2048 + lane * 16;
#pragma unroll
            for (int tj = 0; tj < 4; ++tj)
#pragma unroll
                for (int ks = 0; ks < 2; ++ks)
                    bufs[0][tj][ks] = *(const intx4*)(bp + tj * 2048 + ks * 1024);
        }

#pragma unroll
        for (int s = 0; s < 4; ++s) {
            // prefetch next tile (step s+1, or the dd=64 extra tile on the last step)
            if (s < 3) {
                int coln = ((bx + y * 16 + (s + 1) * 4 + w) & 127) * 64;
                const unsigned char* bp = Qb + (size_t)(coln >> 4) * 2048 + lane * 16;
#pragma unroll
                for (int tj = 0; tj < 4; ++tj)
#pragma unroll
                    for (int ks = 0; ks < 2; ++ks)
                        bufs[(s + 1) & 1][tj][ks] = *(const intx4*)(bp + tj * 2048 + ks * 1024);
            } else if (ext) {
                int coln = (bx + 64) * 64;
                const unsigned char* bp = Qb + (size_t)(coln >> 4) * 2048 + lane * 16;
#pragma unroll
                for (int tj = 0; tj < 4; ++tj)
#pragma unroll
                    for (int ks = 0; ks < 2; ++ks)
                        bufs[0][tj][ks] = *(const intx4*)(bp + tj * 2048 + ks * 1024);
            }

            int csb = (bx + y * 16 + s * 4 + w) & 127;   // col slab index
            int col0 = csb * 64;
            int thrq = (int)((fminf(dmr, slabmin(Dpart, csb)) - 60.f) * 90.f);

            intx4 acc[4][4];
#pragma unroll
            for (int it = 0; it < 4; ++it)
#pragma unroll
                for (int tj = 0; tj < 4; ++tj)
                    acc[it][tj] = (intx4){0, 0, 0, 0};
#pragma unroll
            for (int ks = 0; ks < 2; ++ks)
#pragma unroll
                for (int it = 0; it < 4; ++it)
#pragma unroll
                    for (int tj = 0; tj < 4; ++tj)
                        acc[it][tj] = __builtin_amdgcn_mfma_i32_16x16x64_i8(
                            af[it][ks], bufs[s & 1][tj][ks], acc[it][tj], 0, 0, 0);

            int mx = -2147483647;
#pragma unroll
            for (int it = 0; it < 4; ++it)
#pragma unroll
                for (int tj = 0; tj < 4; ++tj) {
                    int a01 = max(acc[it][tj][0], acc[it][tj][1]);
                    int a23 = max(acc[it][tj][2], acc[it][tj][3]);
                    mx = max(mx, max(a01, a23));
                }

            if (__any(mx > thrq)) {
                bool has_diag = (col0 == row0);   // wave-uniform (dd==0)
                // row side: exp(l - M_row) into PS[row] (self excluded on diag tile)
#pragma unroll
                for (int it = 0; it < 4; ++it)
#pragma unroll
                    for (int r = 0; r < 4; ++r) {
                        int grow = row0 + it * 16 + quad * 4 + r;
                        float Mrow = diag10[grow];
                        float rs = 0.f;
#pragma unroll
                        for (int tj = 0; tj < 4; ++tj) {
                            int gcol = col0 + tj * 16 + l16;
                            float lv = (float)acc[it][tj][r] * (1.f / 90.f);
                            float ev = __expf(lv - Mrow);
                            rs += (grow == gcol) ? 0.f : ev;
                        }
                        rs += __shfl_xor(rs, 1, 16);
                        rs += __shfl_xor(rs, 2, 16);
                        rs += __shfl_xor(rs, 4, 16);
                        rs += __shfl_xor(rs, 8, 16);
                        if (l16 == 0) atomicAdd(&PS[grow], rs);
                    }
                // col side (off-diag tiles only): exp(l - M_col) into PS[col]
                if (!has_diag) {
#pragma unroll
                    for (int tj = 0; tj < 4; ++tj) {
                        int gcol = col0 + tj * 16 + l16;
                        float Mcol = diag10[gcol];
                        float cs_ = 0.f;
#pragma unroll
                        for (int it = 0; it < 4; ++it)
#pragma unroll
                            for (int r = 0; r < 4; ++r)
                                cs_ += __expf((float)acc[it][tj][r] * (1.f / 90.f) - Mcol);
                        cs_ += __shfl_xor(cs_, 16);
                        cs_ += __shfl_xor(cs_, 32);
                        if (quad == 0) atomicAdd(&PS[gcol], cs_);
                    }
                }
            }
        }

        // dd=64 extra tile (unordered pair {bx, bx+64}), off-diag semantics
        if (ext) {
            int col0 = (bx + 64) * 64;
            int thrq = (int)((fminf(dmr, slabmin(Dpart, bx + 64)) - 60.f) * 90.f);
            intx4 acc[4][4];
#pragma unroll
            for (int it = 0; it < 4; ++it)
#pragma unroll
                for (int tj = 0; tj < 4; ++tj)
                    acc[it][tj] = (intx4){0, 0, 0, 0};
#pragma unroll
            for (int ks = 0; ks < 2; ++ks)
#pragma unroll
                for (int it = 0; it < 4; ++it)
#pragma unroll
                    for (int tj = 0; tj < 4; ++tj)
                        acc[it][tj] = __builtin_amdgcn_mfma_i32_16x16x64_i8(
                            af[it][ks], bufs[0][tj][ks], acc[it][tj], 0, 0, 0);

            int mx = -2147483647;
#pragma unroll
            for (int it = 0; it < 4; ++it)
#pragma unroll
                for (int tj = 0; tj < 4; ++tj) {
                    int a01 = max(acc[it][tj][0], acc[it][tj][1]);
                    int a23 = max(acc[it][tj][2], acc[it][tj][3]);
                    mx = max(mx, max(a01, a23));
                }
            if (__any(mx > thrq)) {
#pragma unroll
                for (int it = 0; it < 4; ++it)
#pragma unroll
                    for (int r = 0; r < 4; ++r) {
                        int grow = row0 + it * 16 + quad * 4 + r;
                        float Mrow = diag10[grow];
                        float rs = 0.f;
#pragma unroll
                        for (int tj = 0; tj < 4; ++tj) {
                            float lv = (float)acc[it][tj][r] * (1.f / 90.f);
                            rs += __expf(lv - Mrow);
                        }
                        rs += __shfl_xor(rs, 1, 16);
                        rs += __shfl_xor(rs, 2, 16);
                        rs += __shfl_xor(rs, 4, 16);
                        rs += __shfl_xor(rs, 8, 16);
                        if (l16 == 0) atomicAdd(&PS[grow], rs);
                    }
#pragma unroll
                for (int tj = 0; tj < 4; ++tj) {
                    int gcol = col0 + tj * 16 + l16;
                    float Mcol = diag10[gcol];
                    float cs_ = 0.f;
#pragma unroll
                    for (int it = 0; it < 4; ++it)
#pragma unroll
                        for (int r = 0; r < 4; ++r)
                            cs_ += __expf((float)acc[it][tj][r] * (1.f / 90.f) - Mcol);
                    cs_ += __shfl_xor(cs_, 16);
                    cs_ += __shfl_xor(cs_, 32);
                    if (quad == 0) atomicAdd(&PS[gcol], cs_);
                }
            }
        }
    }

    grid_barrier(bar, 2 * GRID);

    // ================= Phase 3: posdot + log-term + reduce (blocks 0..127) =====
    if (b >= 128) return;
    {
        for (int i = t; i < NCLS * KD; i += TPB) sh.fin.Ss[i] = S[i];
        if (t < NCLS) sh.fin.cs[t] = cnt[t];
        __syncthreads();

        int g = t >> 2, q = t & 3;            // 4 lanes per row
        int row = b * 64 + g;
        int c = tgt[row];
        float dot = 0.f;
#pragma unroll
        for (int i = 0; i < 8; ++i) {
            float4 f = *(const float4*)(F + (size_t)row * KD + i * 16 + q * 4);
            float4 s = *(const float4*)(sh.fin.Ss + c * KD + i * 16 + q * 4);
            dot += f.x * s.x + f.y * s.y + f.z * s.z + f.w * s.w;
        }
        dot += __shfl_xor(dot, 1, 4);
        dot += __shfl_xor(dot, 2, 4);

        float mlp = 0.f;
        if (q == 0) {
            float M = diag10[row];
            float pp = 10.f * dot - M;            // sum over positives of logits
            float T = PS[row];                    // surviving shifted exp mass
            float np = (float)(sh.fin.cs[c] - 1);
            mlp = (np < 0.5f) ? 0.f : (pp - np * (M + __logf(T + 1e-20f))) / np;
        }
#pragma unroll
        for (int off = 32; off >= 1; off >>= 1) mlp += __shfl_xor(mlp, off);
        int lane = t & 63, w = t >> 6;
        if (lane == 0) sh.fin.wsum[w] = mlp;
        __syncthreads();
        if (t == 0) {
            atomicAdd(accg, (sh.fin.wsum[0] + sh.fin.wsum[1]) + (sh.fin.wsum[2] + sh.fin.wsum[3]));
            __threadfence();
            int old = atomicAdd(&cnt[12], 1);   // ticket among 128 final blocks
            if (old == 127) {
                float tot = atomicAdd(accg, 0.0f);   // coherent read of total
                double sp = 0.0, sn = 0.0;
                for (int cc = 0; cc < NCLS; ++cc) {
                    double n = (double)sh.fin.cs[cc];
                    sp += n * (n - 1.0);
                    sn += n * ((double)N - n);
                }
                out[0] = (float)(-(0.1 / 0.07) * ((double)tot / (double)N));
                out[1] = (float)(sp / (double)N);
                out[2] = (float)(sn / (double)N);
            }
        }
    }
}

extern "C" void kernel_launch(void* const* d_in, const int* in_sizes, int n_in,
                              void* d_out, int out_size, void* d_ws, size_t ws_size,
                              hipStream_t stream) {
    const float* F = (const float*)d_in[0];
    const int* tgt = (const int*)d_in[1];
    float* out = (float*)d_out;
    char* ws = (char*)d_ws;

    int* cnt = (int*)(ws);                       // 64 B (ticket at cnt[12])
    float* acc = (float*)(ws + 64);              // 4 B
    float* S = (float*)(ws + 128);               // 5120 B -> ends 5248
    int* bar = (int*)(ws + 6144);                // barrier counter, own cacheline
    float* PS = (float*)(ws + 8192);             // 32 KiB (zeroed in phase 1)
    int* Dpart = (int*)(ws + 49152);             // 2 KiB (per-16-row diag mins)
    float* diag10 = (float*)(ws + 65536);        // 32 KiB
    int* Q = (int*)(ws + (1u << 20));            // 1 MiB (i8 frags of 30*F)

    hipMemsetAsync(ws, 0, 8192, stream);         // cnt + acc + S + bar
    k_fused<<<GRID, TPB, 0, stream>>>(F, tgt, diag10, Q, S, cnt, PS, Dpart, acc, bar, out);
}

// Round 5
// 113.164 us; speedup vs baseline: 2.0562x; 1.4503x over previous
//
#include <hip/hip_runtime.h>

#define N 8192
#define KD 128
#define NCLS 10
#define GRID 512
#define TPB 256

typedef __attribute__((ext_vector_type(4))) int intx4;

// i8 fragment layout (K=64 per MFMA, two ks halves per K=128 row):
//   byte addr = idx16*2048 + ks*1024 + quad*256 + l16*16 + j   (k = ks*64+quad*16+j)
// Q holds rn(30*F) as i8; logit = (qa . qb) / 90.
//
// Coherence scheme (r5): NO __threadfence anywhere. gfx950 agent fences lower to
// whole-L2 writeback/invalidate; 512 leaders x 2 fences x 2 barriers ~= 100us (r4).
// Instead, every cross-phase producer store is a RELAXED AGENT atomic store
// (global_store sc1: write-through to the IF$/MALL coherence point, never dirty in
// L2), and consumers either cache-read addresses never cached pre-barrier (Q,
// diag10, Dpart -> coherent trivially) or use RELAXED AGENT atomic loads for
// atomically-updated data (PS, S, cnt). The grid barrier is then just
// vmcnt-drain + relaxed fetch_add + relaxed poll.

__device__ __forceinline__ float slabmin(const int* __restrict__ Dpart, int slab) {
    float a = fminf(__int_as_float(Dpart[slab * 4 + 0]), __int_as_float(Dpart[slab * 4 + 1]));
    float b = fminf(__int_as_float(Dpart[slab * 4 + 2]), __int_as_float(Dpart[slab * 4 + 3]));
    return fminf(a, b);
}

__device__ __forceinline__ void st_agent(int* p, int v) {
    __hip_atomic_store(p, v, __ATOMIC_RELAXED, __HIP_MEMORY_SCOPE_AGENT);
}
__device__ __forceinline__ void st_agent_f(float* p, float v) {
    __hip_atomic_store(p, v, __ATOMIC_RELAXED, __HIP_MEMORY_SCOPE_AGENT);
}
__device__ __forceinline__ float ld_agent_f(const float* p) {
    return __hip_atomic_load(p, __ATOMIC_RELAXED, __HIP_MEMORY_SCOPE_AGENT);
}
__device__ __forceinline__ int ld_agent(const int* p) {
    return __hip_atomic_load(p, __ATOMIC_RELAXED, __HIP_MEMORY_SCOPE_AGENT);
}

// Fence-free grid barrier (see header comment). The preceding __syncthreads
// already drains each wave's vmcnt (compiler emits s_waitcnt before s_barrier),
// so all sc1 stores of every wave are at the coherence point before arrival.
__device__ __forceinline__ void grid_barrier(int* bar, int target) {
    __syncthreads();
    if (threadIdx.x == 0) {
        asm volatile("s_waitcnt vmcnt(0)" ::: "memory");
        __hip_atomic_fetch_add(bar, 1, __ATOMIC_RELAXED, __HIP_MEMORY_SCOPE_AGENT);
        while (__hip_atomic_load(bar, __ATOMIC_RELAXED, __HIP_MEMORY_SCOPE_AGENT) < target)
            __builtin_amdgcn_s_sleep(4);
    }
    __syncthreads();
}

__global__ __launch_bounds__(TPB, 2) void k_fused(const float* __restrict__ F,
                                                  const int* __restrict__ tgt,
                                                  float* __restrict__ diag10,
                                                  int* __restrict__ Q,
                                                  float* __restrict__ S,
                                                  int* __restrict__ cnt,
                                                  float* __restrict__ PS,
                                                  int* __restrict__ Dpart,
                                                  float* __restrict__ accg,
                                                  int* __restrict__ bar,
                                                  float* __restrict__ out) {
    const unsigned char* Qb = (const unsigned char*)Q;
    int b = blockIdx.x;
    int t = threadIdx.x;

    __shared__ int bmin;
    __shared__ union {
        struct { int lh[NCLS]; float red[2][NCLS][KD]; } cls;          // phase 1b
        struct { float Ss[NCLS * KD]; int cs[NCLS]; float wsum[4]; } fin; // phase 3
    } sh;

    // ================= Phase 1a: i8 convert, 16 rows per block =================
    {
        int row0 = b * 16;
        if (t == 0) bmin = 0x7f7fffff;       // +3.4e38 bits
        __syncthreads();
        if (t < 16) st_agent_f(&PS[row0 + t], 0.f);
        int col4 = t & 31;   // which float4 of the row (k = col4*4)
        int rg = t >> 5;     // 0..7
#pragma unroll
        for (int sw = 0; sw < 2; ++sw) {
            int row = row0 + sw * 8 + rg;
            float4 v = *(const float4*)(F + (size_t)row * KD + col4 * 4);
            float sq = v.x * v.x + v.y * v.y + v.z * v.z + v.w * v.w;
#pragma unroll
            for (int off = 16; off >= 1; off >>= 1) sq += __shfl_xor(sq, off);
            if (col4 == 0) {
                float dg = 10.f * sq;
                st_agent_f(&diag10[row], dg);
                atomicMin(&bmin, __float_as_int(dg));   // LDS atomic, 16/block
            }
            // i8 quantize: q = rn(30*clamp(v, +-4.2))
            int q0 = __float2int_rn(30.f * fminf(fmaxf(v.x, -4.2f), 4.2f));
            int q1 = __float2int_rn(30.f * fminf(fmaxf(v.y, -4.2f), 4.2f));
            int q2 = __float2int_rn(30.f * fminf(fmaxf(v.z, -4.2f), 4.2f));
            int q3 = __float2int_rn(30.f * fminf(fmaxf(v.w, -4.2f), 4.2f));
            int dq = (q0 & 255) | ((q1 & 255) << 8) | ((q2 & 255) << 16) | ((q3 & 255) << 24);
            int idx = (row >> 4) * 512 + (col4 >> 4) * 256 + ((col4 >> 2) & 3) * 64 +
                      (row & 15) * 4 + (col4 & 3);
            st_agent(&Q[idx], dq);
        }
        __syncthreads();
        if (t == 0) st_agent(&Dpart[b], bmin);
    }

    // ================= Phase 1b: class sums (blocks 0..127, 64 rows each) ======
    if (b < 128) {
        int row0 = b * 64;
        int k = t & 127, h = t >> 7;
        if (t < NCLS) sh.cls.lh[t] = 0;
        __syncthreads();
        if (t < 64) atomicAdd(&sh.cls.lh[tgt[row0 + t]], 1);
        float local[NCLS];
#pragma unroll
        for (int c = 0; c < NCLS; ++c) local[c] = 0.f;
        for (int ii = 0; ii < 32; ++ii) {
            int row = row0 + h * 32 + ii;
            float v = F[(size_t)row * KD + k];
            int c = tgt[row];
#pragma unroll
            for (int cc = 0; cc < NCLS; ++cc) local[cc] += (cc == c) ? v : 0.f;
        }
#pragma unroll
        for (int cc = 0; cc < NCLS; ++cc) sh.cls.red[h][cc][k] = local[cc];
        __syncthreads();
        if (h == 0) {
#pragma unroll
            for (int cc = 0; cc < NCLS; ++cc)
                atomicAdd(&S[cc * KD + k], sh.cls.red[0][cc][k] + sh.cls.red[1][cc][k]);
            if (t < NCLS) atomicAdd(&cnt[t], sh.cls.lh[t]);
        }
    }

    grid_barrier(bar, GRID);

    // ================= Phase 2: symmetric-half i8 MFMA pair sweep ==============
    {
        int bx = b & 127, y = b >> 7;
        int w = t >> 6, lane = t & 63;
        int quad = lane >> 4, l16 = lane & 15;
        int row0 = bx * 64;

        float dmr = slabmin(Dpart, bx);   // row-slab min diag

        // A fragments: af[it][ks] for rows row0 + it*16 + l16
        intx4 af[4][2];
#pragma unroll
        for (int it = 0; it < 4; ++it)
#pragma unroll
            for (int ks = 0; ks < 2; ++ks)
                af[it][ks] =
                    *(const intx4*)(Qb + (size_t)(bx * 4 + it) * 2048 + ks * 1024 + lane * 16);

        bool ext = (y == 0) && (bx < 64) && (w == 0);   // handles the dd=64 tile

        // double-buffered B fragments
        intx4 bufs[2][4][2];
        {   // prologue: load step 0 (dd = y*16 + w)
            int col0 = ((bx + y * 16 + w) & 127) * 64;
            const unsigned char* bp = Qb + (size_t)(col0 >> 4) * 2048 + lane * 16;
#pragma unroll
            for (int tj = 0; tj < 4; ++tj)
#pragma unroll
                for (int ks = 0; ks < 2; ++ks)
                    bufs[0][tj][ks] = *(const intx4*)(bp + tj * 2048 + ks * 1024);
        }

#pragma unroll
        for (int s = 0; s < 4; ++s) {
            // prefetch next tile (step s+1, or the dd=64 extra tile on the last step)
            if (s < 3) {
                int coln = ((bx + y * 16 + (s + 1) * 4 + w) & 127) * 64;
                const unsigned char* bp = Qb + (size_t)(coln >> 4) * 2048 + lane * 16;
#pragma unroll
                for (int tj = 0; tj < 4; ++tj)
#pragma unroll
                    for (int ks = 0; ks < 2; ++ks)
                        bufs[(s + 1) & 1][tj][ks] = *(const intx4*)(bp + tj * 2048 + ks * 1024);
            } else if (ext) {
                int coln = (bx + 64) * 64;
                const unsigned char* bp = Qb + (size_t)(coln >> 4) * 2048 + lane * 16;
#pragma unroll
                for (int tj = 0; tj < 4; ++tj)
#pragma unroll
                    for (int ks = 0; ks < 2; ++ks)
                        bufs[0][tj][ks] = *(const intx4*)(bp + tj * 2048 + ks * 1024);
            }

            int csb = (bx + y * 16 + s * 4 + w) & 127;   // col slab index
            int col0 = csb * 64;
            int thrq = (int)((fminf(dmr, slabmin(Dpart, csb)) - 60.f) * 90.f);

            intx4 acc[4][4];
#pragma unroll
            for (int it = 0; it < 4; ++it)
#pragma unroll
                for (int tj = 0; tj < 4; ++tj)
                    acc[it][tj] = (intx4){0, 0, 0, 0};
#pragma unroll
            for (int ks = 0; ks < 2; ++ks)
#pragma unroll
                for (int it = 0; it < 4; ++it)
#pragma unroll
                    for (int tj = 0; tj < 4; ++tj)
                        acc[it][tj] = __builtin_amdgcn_mfma_i32_16x16x64_i8(
                            af[it][ks], bufs[s & 1][tj][ks], acc[it][tj], 0, 0, 0);

            int mx = -2147483647;
#pragma unroll
            for (int it = 0; it < 4; ++it)
#pragma unroll
                for (int tj = 0; tj < 4; ++tj) {
                    int a01 = max(acc[it][tj][0], acc[it][tj][1]);
                    int a23 = max(acc[it][tj][2], acc[it][tj][3]);
                    mx = max(mx, max(a01, a23));
                }

            if (__any(mx > thrq)) {
                bool has_diag = (col0 == row0);   // wave-uniform (dd==0)
                // row side: exp(l - M_row) into PS[row] (self excluded on diag tile)
#pragma unroll
                for (int it = 0; it < 4; ++it)
#pragma unroll
                    for (int r = 0; r < 4; ++r) {
                        int grow = row0 + it * 16 + quad * 4 + r;
                        float Mrow = diag10[grow];
                        float rs = 0.f;
#pragma unroll
                        for (int tj = 0; tj < 4; ++tj) {
                            int gcol = col0 + tj * 16 + l16;
                            float lv = (float)acc[it][tj][r] * (1.f / 90.f);
                            float ev = __expf(lv - Mrow);
                            rs += (grow == gcol) ? 0.f : ev;
                        }
                        rs += __shfl_xor(rs, 1, 16);
                        rs += __shfl_xor(rs, 2, 16);
                        rs += __shfl_xor(rs, 4, 16);
                        rs += __shfl_xor(rs, 8, 16);
                        if (l16 == 0) atomicAdd(&PS[grow], rs);
                    }
                // col side (off-diag tiles only): exp(l - M_col) into PS[col]
                if (!has_diag) {
#pragma unroll
                    for (int tj = 0; tj < 4; ++tj) {
                        int gcol = col0 + tj * 16 + l16;
                        float Mcol = diag10[gcol];
                        float cs_ = 0.f;
#pragma unroll
                        for (int it = 0; it < 4; ++it)
#pragma unroll
                            for (int r = 0; r < 4; ++r)
                                cs_ += __expf((float)acc[it][tj][r] * (1.f / 90.f) - Mcol);
                        cs_ += __shfl_xor(cs_, 16);
                        cs_ += __shfl_xor(cs_, 32);
                        if (quad == 0) atomicAdd(&PS[gcol], cs_);
                    }
                }
            }
        }

        // dd=64 extra tile (unordered pair {bx, bx+64}), off-diag semantics
        if (ext) {
            int col0 = (bx + 64) * 64;
            int thrq = (int)((fminf(dmr, slabmin(Dpart, bx + 64)) - 60.f) * 90.f);
            intx4 acc[4][4];
#pragma unroll
            for (int it = 0; it < 4; ++it)
#pragma unroll
                for (int tj = 0; tj < 4; ++tj)
                    acc[it][tj] = (intx4){0, 0, 0, 0};
#pragma unroll
            for (int ks = 0; ks < 2; ++ks)
#pragma unroll
                for (int it = 0; it < 4; ++it)
#pragma unroll
                    for (int tj = 0; tj < 4; ++tj)
                        acc[it][tj] = __builtin_amdgcn_mfma_i32_16x16x64_i8(
                            af[it][ks], bufs[0][tj][ks], acc[it][tj], 0, 0, 0);

            int mx = -2147483647;
#pragma unroll
            for (int it = 0; it < 4; ++it)
#pragma unroll
                for (int tj = 0; tj < 4; ++tj) {
                    int a01 = max(acc[it][tj][0], acc[it][tj][1]);
                    int a23 = max(acc[it][tj][2], acc[it][tj][3]);
                    mx = max(mx, max(a01, a23));
                }
            if (__any(mx > thrq)) {
#pragma unroll
                for (int it = 0; it < 4; ++it)
#pragma unroll
                    for (int r = 0; r < 4; ++r) {
                        int grow = row0 + it * 16 + quad * 4 + r;
                        float Mrow = diag10[grow];
                        float rs = 0.f;
#pragma unroll
                        for (int tj = 0; tj < 4; ++tj) {
                            float lv = (float)acc[it][tj][r] * (1.f / 90.f);
                            rs += __expf(lv - Mrow);
                        }
                        rs += __shfl_xor(rs, 1, 16);
                        rs += __shfl_xor(rs, 2, 16);
                        rs += __shfl_xor(rs, 4, 16);
                        rs += __shfl_xor(rs, 8, 16);
                        if (l16 == 0) atomicAdd(&PS[grow], rs);
                    }
#pragma unroll
                for (int tj = 0; tj < 4; ++tj) {
                    int gcol = col0 + tj * 16 + l16;
                    float Mcol = diag10[gcol];
                    float cs_ = 0.f;
#pragma unroll
                    for (int it = 0; it < 4; ++it)
#pragma unroll
                        for (int r = 0; r < 4; ++r)
                            cs_ += __expf((float)acc[it][tj][r] * (1.f / 90.f) - Mcol);
                    cs_ += __shfl_xor(cs_, 16);
                    cs_ += __shfl_xor(cs_, 32);
                    if (quad == 0) atomicAdd(&PS[gcol], cs_);
                }
            }
        }
    }

    grid_barrier(bar, 2 * GRID);

    // ================= Phase 3: posdot + log-term + reduce (blocks 0..127) =====
    if (b >= 128) return;
    {
        // S/cnt/PS were produced by coherence-point atomics: read with agent-scope
        // (L2-bypass) loads so no stale clean line can be hit.
        for (int i = t; i < NCLS * KD; i += TPB) sh.fin.Ss[i] = ld_agent_f(&S[i]);
        if (t < NCLS) sh.fin.cs[t] = ld_agent(&cnt[t]);
        __syncthreads();

        int g = t >> 2, q = t & 3;            // 4 lanes per row
        int row = b * 64 + g;
        int c = tgt[row];
        float dot = 0.f;
#pragma unroll
        for (int i = 0; i < 8; ++i) {
            float4 f = *(const float4*)(F + (size_t)row * KD + i * 16 + q * 4);
            float4 s = *(const float4*)(sh.fin.Ss + c * KD + i * 16 + q * 4);
            dot += f.x * s.x + f.y * s.y + f.z * s.z + f.w * s.w;
        }
        dot += __shfl_xor(dot, 1, 4);
        dot += __shfl_xor(dot, 2, 4);

        float mlp = 0.f;
        if (q == 0) {
            float M = diag10[row];
            float pp = 10.f * dot - M;            // sum over positives of logits
            float T = ld_agent_f(&PS[row]);       // surviving shifted exp mass
            float np = (float)(sh.fin.cs[c] - 1);
            mlp = (np < 0.5f) ? 0.f : (pp - np * (M + __logf(T + 1e-20f))) / np;
        }
#pragma unroll
        for (int off = 32; off >= 1; off >>= 1) mlp += __shfl_xor(mlp, off);
        int lane = t & 63, w = t >> 6;
        if (lane == 0) sh.fin.wsum[w] = mlp;
        __syncthreads();
        if (t == 0) {
            atomicAdd(accg, (sh.fin.wsum[0] + sh.fin.wsum[1]) + (sh.fin.wsum[2] + sh.fin.wsum[3]));
            int old = atomicAdd(&cnt[12], 1);   // ticket among 128 final blocks
            if (old == 127) {
                float tot = atomicAdd(accg, 0.0f);   // coherent read of total
                double sp = 0.0, sn = 0.0;
                for (int cc = 0; cc < NCLS; ++cc) {
                    double n = (double)sh.fin.cs[cc];
                    sp += n * (n - 1.0);
                    sn += n * ((double)N - n);
                }
                out[0] = (float)(-(0.1 / 0.07) * ((double)tot / (double)N));
                out[1] = (float)(sp / (double)N);
                out[2] = (float)(sn / (double)N);
            }
        }
    }
}

extern "C" void kernel_launch(void* const* d_in, const int* in_sizes, int n_in,
                              void* d_out, int out_size, void* d_ws, size_t ws_size,
                              hipStream_t stream) {
    const float* F = (const float*)d_in[0];
    const int* tgt = (const int*)d_in[1];
    float* out = (float*)d_out;
    char* ws = (char*)d_ws;

    int* cnt = (int*)(ws);                       // 64 B (ticket at cnt[12])
    float* acc = (float*)(ws + 64);              // 4 B
    float* S = (float*)(ws + 128);               // 5120 B -> ends 5248
    int* bar = (int*)(ws + 6144);                // barrier counter, own cacheline
    float* PS = (float*)(ws + 8192);             // 32 KiB (zeroed in phase 1)
    int* Dpart = (int*)(ws + 49152);             // 2 KiB (per-16-row diag mins)
    float* diag10 = (float*)(ws + 65536);        // 32 KiB
    int* Q = (int*)(ws + (1u << 20));            // 1 MiB (i8 frags of 30*F)

    hipMemsetAsync(ws, 0, 8192, stream);         // cnt + acc + S + bar
    k_fused<<<GRID, TPB, 0, stream>>>(F, tgt, diag10, Q, S, cnt, PS, Dpart, acc, bar, out);
}

// Round 6
// 88.196 us; speedup vs baseline: 2.6383x; 1.2831x over previous
//
#include <hip/hip_runtime.h>

#define N 8192
#define KD 128
#define NCLS 10
#define GRID 512
#define TPB 256

typedef __attribute__((ext_vector_type(4))) int intx4;

// i8 fragment layout (K=64 per MFMA, two ks halves per K=128 row):
//   byte addr = idx16*2048 + ks*1024 + quad*256 + l16*16 + j   (k = ks*64+quad*16+j)
// Q holds rn(30*F) as i8; logit = (qa . qb) / 90.
//
// Coherence scheme (r5/r6): NO __threadfence anywhere (agent fences = whole-L2
// writeback/invalidate x 512 leaders ~= 100us, r4). Producers store cross-phase
// data with RELAXED AGENT atomic stores (write-through to MALL, never dirty in
// L2); consumers cache-read never-before-cached lines (Q/diag10/Dpart) or use
// RELAXED AGENT loads (PS/S/cnt).
// Barrier scheme (r6): arrival counter and release flag are SEPARATE lines.
// r5 polled the counter itself -> arriving fetch_adds queued behind ~500
// pollers' reads at the MALL atomic unit (~20us/barrier). Now: fetch_add on a
// write-only counter; last arriver stores epoch to 8 flag copies (distinct
// cachelines); pollers read flag[b&7]. Blocks 0..127 overlap phase-1b class
// sums with barrier-1 spin; blocks >=128 skip the barrier-2 wait entirely.

__device__ __forceinline__ float slabmin(const int* __restrict__ Dpart, int slab) {
    float a = fminf(__int_as_float(Dpart[slab * 4 + 0]), __int_as_float(Dpart[slab * 4 + 1]));
    float b = fminf(__int_as_float(Dpart[slab * 4 + 2]), __int_as_float(Dpart[slab * 4 + 3]));
    return fminf(a, b);
}

__device__ __forceinline__ void st_agent(int* p, int v) {
    __hip_atomic_store(p, v, __ATOMIC_RELAXED, __HIP_MEMORY_SCOPE_AGENT);
}
__device__ __forceinline__ void st_agent_f(float* p, float v) {
    __hip_atomic_store(p, v, __ATOMIC_RELAXED, __HIP_MEMORY_SCOPE_AGENT);
}
__device__ __forceinline__ float ld_agent_f(const float* p) {
    return __hip_atomic_load(p, __ATOMIC_RELAXED, __HIP_MEMORY_SCOPE_AGENT);
}
__device__ __forceinline__ int ld_agent(const int* p) {
    return __hip_atomic_load(p, __ATOMIC_RELAXED, __HIP_MEMORY_SCOPE_AGENT);
}

// Arrival: returns true iff this was the last arriver. Caller (t==0) must have
// drained vmcnt so its block's prior sc1 stores are at the coherence point.
__device__ __forceinline__ bool arrive_last(int* ctr) {
    int old = __hip_atomic_fetch_add(ctr, 1, __ATOMIC_RELAXED, __HIP_MEMORY_SCOPE_AGENT);
    return old == GRID - 1;
}
__device__ __forceinline__ void release_flags(int* flagv, int epoch) {
#pragma unroll
    for (int i = 0; i < 8; ++i) st_agent(&flagv[i * 32], epoch);
}
__device__ __forceinline__ void wait_flag(const int* flagv, int b, int epoch) {
    while (ld_agent(&flagv[(b & 7) * 32]) < epoch) __builtin_amdgcn_s_sleep(8);
}

__global__ __launch_bounds__(TPB, 2) void k_fused(const float* __restrict__ F,
                                                  const int* __restrict__ tgt,
                                                  float* __restrict__ diag10,
                                                  int* __restrict__ Q,
                                                  float* __restrict__ S,
                                                  int* __restrict__ cnt,
                                                  float* __restrict__ PS,
                                                  int* __restrict__ Dpart,
                                                  float* __restrict__ accg,
                                                  int* __restrict__ bar1,
                                                  int* __restrict__ bar2,
                                                  int* __restrict__ flagv,
                                                  float* __restrict__ out) {
    const unsigned char* Qb = (const unsigned char*)Q;
    int b = blockIdx.x;
    int t = threadIdx.x;

    __shared__ int bmin;
    __shared__ union {
        struct { int lh[NCLS]; float red[2][NCLS][KD]; } cls;          // phase 1b
        struct { float Ss[NCLS * KD]; int cs[NCLS]; float wsum[4]; } fin; // phase 3
    } sh;

    // ================= Phase 1a: i8 convert, 16 rows per block =================
    {
        int row0 = b * 16;
        if (t == 0) bmin = 0x7f7fffff;       // +3.4e38 bits
        __syncthreads();
        if (t < 16) st_agent_f(&PS[row0 + t], 0.f);
        int col4 = t & 31;   // which float4 of the row (k = col4*4)
        int rg = t >> 5;     // 0..7
#pragma unroll
        for (int sw = 0; sw < 2; ++sw) {
            int row = row0 + sw * 8 + rg;
            float4 v = *(const float4*)(F + (size_t)row * KD + col4 * 4);
            float sq = v.x * v.x + v.y * v.y + v.z * v.z + v.w * v.w;
#pragma unroll
            for (int off = 16; off >= 1; off >>= 1) sq += __shfl_xor(sq, off);
            if (col4 == 0) {
                float dg = 10.f * sq;
                st_agent_f(&diag10[row], dg);
                atomicMin(&bmin, __float_as_int(dg));   // LDS atomic, 16/block
            }
            // i8 quantize: q = rn(30*clamp(v, +-4.2))
            int q0 = __float2int_rn(30.f * fminf(fmaxf(v.x, -4.2f), 4.2f));
            int q1 = __float2int_rn(30.f * fminf(fmaxf(v.y, -4.2f), 4.2f));
            int q2 = __float2int_rn(30.f * fminf(fmaxf(v.z, -4.2f), 4.2f));
            int q3 = __float2int_rn(30.f * fminf(fmaxf(v.w, -4.2f), 4.2f));
            int dq = (q0 & 255) | ((q1 & 255) << 8) | ((q2 & 255) << 16) | ((q3 & 255) << 24);
            int idx = (row >> 4) * 512 + (col4 >> 4) * 256 + ((col4 >> 2) & 3) * 64 +
                      (row & 15) * 4 + (col4 & 3);
            st_agent(&Q[idx], dq);
        }
        __syncthreads();   // all waves' Q/PS/diag10 stores drained (waitcnt before s_barrier)
        if (t == 0) {
            st_agent(&Dpart[b], bmin);
            asm volatile("s_waitcnt vmcnt(0)" ::: "memory");
            if (arrive_last(bar1)) release_flags(flagv, 1);   // barrier-1 ARRIVAL (early)
        }
    }

    // ====== Phase 1b: class sums (blocks 0..127) — overlapped with b1 spin =====
    if (b < 128) {
        int row0 = b * 64;
        int k = t & 127, h = t >> 7;
        if (t < NCLS) sh.cls.lh[t] = 0;
        __syncthreads();
        if (t < 64) atomicAdd(&sh.cls.lh[tgt[row0 + t]], 1);
        float local[NCLS];
#pragma unroll
        for (int c = 0; c < NCLS; ++c) local[c] = 0.f;
        for (int ii = 0; ii < 32; ++ii) {
            int row = row0 + h * 32 + ii;
            float v = F[(size_t)row * KD + k];
            int c = tgt[row];
#pragma unroll
            for (int cc = 0; cc < NCLS; ++cc) local[cc] += (cc == c) ? v : 0.f;
        }
#pragma unroll
        for (int cc = 0; cc < NCLS; ++cc) sh.cls.red[h][cc][k] = local[cc];
        __syncthreads();
        if (h == 0) {
#pragma unroll
            for (int cc = 0; cc < NCLS; ++cc)
                atomicAdd(&S[cc * KD + k], sh.cls.red[0][cc][k] + sh.cls.red[1][cc][k]);
            if (t < NCLS) atomicAdd(&cnt[t], sh.cls.lh[t]);
        }
    }

    // barrier-1 WAIT (poll spread release flags; counter line has no readers)
    if (t == 0) wait_flag(flagv, b, 1);
    __syncthreads();

    // ================= Phase 2: symmetric-half i8 MFMA pair sweep ==============
    {
        int bx = b & 127, y = b >> 7;
        int w = t >> 6, lane = t & 63;
        int quad = lane >> 4, l16 = lane & 15;
        int row0 = bx * 64;

        float dmr = slabmin(Dpart, bx);   // row-slab min diag

        // A fragments: af[it][ks] for rows row0 + it*16 + l16
        intx4 af[4][2];
#pragma unroll
        for (int it = 0; it < 4; ++it)
#pragma unroll
            for (int ks = 0; ks < 2; ++ks)
                af[it][ks] =
                    *(const intx4*)(Qb + (size_t)(bx * 4 + it) * 2048 + ks * 1024 + lane * 16);

        bool ext = (y == 0) && (bx < 64) && (w == 0);   // handles the dd=64 tile

        // double-buffered B fragments
        intx4 bufs[2][4][2];
        {   // prologue: load step 0 (dd = y*16 + w)
            int col0 = ((bx + y * 16 + w) & 127) * 64;
            const unsigned char* bp = Qb + (size_t)(col0 >> 4) * 2048 + lane * 16;
#pragma unroll
            for (int tj = 0; tj < 4; ++tj)
#pragma unroll
                for (int ks = 0; ks < 2; ++ks)
                    bufs[0][tj][ks] = *(const intx4*)(bp + tj * 2048 + ks * 1024);
        }

#pragma unroll
        for (int s = 0; s < 4; ++s) {
            // prefetch next tile (step s+1, or the dd=64 extra tile on the last step)
            if (s < 3) {
                int coln = ((bx + y * 16 + (s + 1) * 4 + w) & 127) * 64;
                const unsigned char* bp = Qb + (size_t)(coln >> 4) * 2048 + lane * 16;
#pragma unroll
                for (int tj = 0; tj < 4; ++tj)
#pragma unroll
                    for (int ks = 0; ks < 2; ++ks)
                        bufs[(s + 1) & 1][tj][ks] = *(const intx4*)(bp + tj * 2048 + ks * 1024);
            } else if (ext) {
                int coln = (bx + 64) * 64;
                const unsigned char* bp = Qb + (size_t)(coln >> 4) * 2048 + lane * 16;
#pragma unroll
                for (int tj = 0; tj < 4; ++tj)
#pragma unroll
                    for (int ks = 0; ks < 2; ++ks)
                        bufs[0][tj][ks] = *(const intx4*)(bp + tj * 2048 + ks * 1024);
            }

            int csb = (bx + y * 16 + s * 4 + w) & 127;   // col slab index
            int col0 = csb * 64;
            int thrq = (int)((fminf(dmr, slabmin(Dpart, csb)) - 60.f) * 90.f);

            intx4 acc[4][4];
#pragma unroll
            for (int it = 0; it < 4; ++it)
#pragma unroll
                for (int tj = 0; tj < 4; ++tj)
                    acc[it][tj] = (intx4){0, 0, 0, 0};
#pragma unroll
            for (int ks = 0; ks < 2; ++ks)
#pragma unroll
                for (int it = 0; it < 4; ++it)
#pragma unroll
                    for (int tj = 0; tj < 4; ++tj)
                        acc[it][tj] = __builtin_amdgcn_mfma_i32_16x16x64_i8(
                            af[it][ks], bufs[s & 1][tj][ks], acc[it][tj], 0, 0, 0);

            int mx = -2147483647;
#pragma unroll
            for (int it = 0; it < 4; ++it)
#pragma unroll
                for (int tj = 0; tj < 4; ++tj) {
                    int a01 = max(acc[it][tj][0], acc[it][tj][1]);
                    int a23 = max(acc[it][tj][2], acc[it][tj][3]);
                    mx = max(mx, max(a01, a23));
                }

            if (__any(mx > thrq)) {
                bool has_diag = (col0 == row0);   // wave-uniform (dd==0)
                // row side: exp(l - M_row) into PS[row] (self excluded on diag tile)
#pragma unroll
                for (int it = 0; it < 4; ++it)
#pragma unroll
                    for (int r = 0; r < 4; ++r) {
                        int grow = row0 + it * 16 + quad * 4 + r;
                        float Mrow = diag10[grow];
                        float rs = 0.f;
#pragma unroll
                        for (int tj = 0; tj < 4; ++tj) {
                            int gcol = col0 + tj * 16 + l16;
                            float lv = (float)acc[it][tj][r] * (1.f / 90.f);
                            float ev = __expf(lv - Mrow);
                            rs += (grow == gcol) ? 0.f : ev;
                        }
                        rs += __shfl_xor(rs, 1, 16);
                        rs += __shfl_xor(rs, 2, 16);
                        rs += __shfl_xor(rs, 4, 16);
                        rs += __shfl_xor(rs, 8, 16);
                        if (l16 == 0) atomicAdd(&PS[grow], rs);
                    }
                // col side (off-diag tiles only): exp(l - M_col) into PS[col]
                if (!has_diag) {
#pragma unroll
                    for (int tj = 0; tj < 4; ++tj) {
                        int gcol = col0 + tj * 16 + l16;
                        float Mcol = diag10[gcol];
                        float cs_ = 0.f;
#pragma unroll
                        for (int it = 0; it < 4; ++it)
#pragma unroll
                            for (int r = 0; r < 4; ++r)
                                cs_ += __expf((float)acc[it][tj][r] * (1.f / 90.f) - Mcol);
                        cs_ += __shfl_xor(cs_, 16);
                        cs_ += __shfl_xor(cs_, 32);
                        if (quad == 0) atomicAdd(&PS[gcol], cs_);
                    }
                }
            }
        }

        // dd=64 extra tile (unordered pair {bx, bx+64}), off-diag semantics
        if (ext) {
            int col0 = (bx + 64) * 64;
            int thrq = (int)((fminf(dmr, slabmin(Dpart, bx + 64)) - 60.f) * 90.f);
            intx4 acc[4][4];
#pragma unroll
            for (int it = 0; it < 4; ++it)
#pragma unroll
                for (int tj = 0; tj < 4; ++tj)
                    acc[it][tj] = (intx4){0, 0, 0, 0};
#pragma unroll
            for (int ks = 0; ks < 2; ++ks)
#pragma unroll
                for (int it = 0; it < 4; ++it)
#pragma unroll
                    for (int tj = 0; tj < 4; ++tj)
                        acc[it][tj] = __builtin_amdgcn_mfma_i32_16x16x64_i8(
                            af[it][ks], bufs[0][tj][ks], acc[it][tj], 0, 0, 0);

            int mx = -2147483647;
#pragma unroll
            for (int it = 0; it < 4; ++it)
#pragma unroll
                for (int tj = 0; tj < 4; ++tj) {
                    int a01 = max(acc[it][tj][0], acc[it][tj][1]);
                    int a23 = max(acc[it][tj][2], acc[it][tj][3]);
                    mx = max(mx, max(a01, a23));
                }
            if (__any(mx > thrq)) {
#pragma unroll
                for (int it = 0; it < 4; ++it)
#pragma unroll
                    for (int r = 0; r < 4; ++r) {
                        int grow = row0 + it * 16 + quad * 4 + r;
                        float Mrow = diag10[grow];
                        float rs = 0.f;
#pragma unroll
                        for (int tj = 0; tj < 4; ++tj) {
                            float lv = (float)acc[it][tj][r] * (1.f / 90.f);
                            rs += __expf(lv - Mrow);
                        }
                        rs += __shfl_xor(rs, 1, 16);
                        rs += __shfl_xor(rs, 2, 16);
                        rs += __shfl_xor(rs, 4, 16);
                        rs += __shfl_xor(rs, 8, 16);
                        if (l16 == 0) atomicAdd(&PS[grow], rs);
                    }
#pragma unroll
                for (int tj = 0; tj < 4; ++tj) {
                    int gcol = col0 + tj * 16 + l16;
                    float Mcol = diag10[gcol];
                    float cs_ = 0.f;
#pragma unroll
                    for (int it = 0; it < 4; ++it)
#pragma unroll
                        for (int r = 0; r < 4; ++r)
                            cs_ += __expf((float)acc[it][tj][r] * (1.f / 90.f) - Mcol);
                    cs_ += __shfl_xor(cs_, 16);
                    cs_ += __shfl_xor(cs_, 32);
                    if (quad == 0) atomicAdd(&PS[gcol], cs_);
                }
            }
        }
    }

    // ===== barrier 2: everyone arrives; only phase-3 blocks (b<128) wait =======
    __syncthreads();   // drains each wave's phase-2 PS atomics
    if (t == 0) {
        asm volatile("s_waitcnt vmcnt(0)" ::: "memory");
        if (arrive_last(bar2)) release_flags(flagv, 2);
    }
    if (b >= 128) return;

    // ================= Phase 3: posdot + log-term + reduce (blocks 0..127) =====
    {
        // Prefetch barrier-independent data while waiting for the release flag.
        int g = t >> 2, q = t & 3;            // 4 lanes per row
        int row = b * 64 + g;
        int c = tgt[row];
        float4 ff[8];
#pragma unroll
        for (int i = 0; i < 8; ++i)
            ff[i] = *(const float4*)(F + (size_t)row * KD + i * 16 + q * 4);
        float M = diag10[row];

        if (t == 0) wait_flag(flagv, b, 2);
        __syncthreads();

        // S/cnt/PS were produced by coherence-point atomics: read with agent-scope
        // (L2-bypass) loads so no stale clean line can be hit.
        for (int i = t; i < NCLS * KD; i += TPB) sh.fin.Ss[i] = ld_agent_f(&S[i]);
        if (t < NCLS) sh.fin.cs[t] = ld_agent(&cnt[t]);
        __syncthreads();

        float dot = 0.f;
#pragma unroll
        for (int i = 0; i < 8; ++i) {
            float4 s = *(const float4*)(sh.fin.Ss + c * KD + i * 16 + q * 4);
            dot += ff[i].x * s.x + ff[i].y * s.y + ff[i].z * s.z + ff[i].w * s.w;
        }
        dot += __shfl_xor(dot, 1, 4);
        dot += __shfl_xor(dot, 2, 4);

        float mlp = 0.f;
        if (q == 0) {
            float pp = 10.f * dot - M;            // sum over positives of logits
            float T = ld_agent_f(&PS[row]);       // surviving shifted exp mass
            float np = (float)(sh.fin.cs[c] - 1);
            mlp = (np < 0.5f) ? 0.f : (pp - np * (M + __logf(T + 1e-20f))) / np;
        }
#pragma unroll
        for (int off = 32; off >= 1; off >>= 1) mlp += __shfl_xor(mlp, off);
        int lane = t & 63, w = t >> 6;
        if (lane == 0) sh.fin.wsum[w] = mlp;
        __syncthreads();
        if (t == 0) {
            atomicAdd(accg, (sh.fin.wsum[0] + sh.fin.wsum[1]) + (sh.fin.wsum[2] + sh.fin.wsum[3]));
            asm volatile("s_waitcnt vmcnt(0)" ::: "memory");   // accg add at MALL before ticket
            int old = atomicAdd(&cnt[12], 1);   // ticket among 128 final blocks
            if (old == 127) {
                float tot = atomicAdd(accg, 0.0f);   // coherent read of total
                double sp = 0.0, sn = 0.0;
                for (int cc = 0; cc < NCLS; ++cc) {
                    double n = (double)sh.fin.cs[cc];
                    sp += n * (n - 1.0);
                    sn += n * ((double)N - n);
                }
                out[0] = (float)(-(0.1 / 0.07) * ((double)tot / (double)N));
                out[1] = (float)(sp / (double)N);
                out[2] = (float)(sn / (double)N);
            }
        }
    }
}

extern "C" void kernel_launch(void* const* d_in, const int* in_sizes, int n_in,
                              void* d_out, int out_size, void* d_ws, size_t ws_size,
                              hipStream_t stream) {
    const float* F = (const float*)d_in[0];
    const int* tgt = (const int*)d_in[1];
    float* out = (float*)d_out;
    char* ws = (char*)d_ws;

    int* cnt = (int*)(ws);                       // 64 B (ticket at cnt[12])
    float* acc = (float*)(ws + 64);              // 4 B
    float* S = (float*)(ws + 128);               // 5120 B -> ends 5248
    int* bar1 = (int*)(ws + 6144);               // arrival counter 1 (own line, write-only)
    int* bar2 = (int*)(ws + 6272);               // arrival counter 2 (own line, write-only)
    int* flagv = (int*)(ws + 6400);              // 8 release-flag copies, 128 B apart
    float* PS = (float*)(ws + 8192);             // 32 KiB (zeroed in phase 1)
    int* Dpart = (int*)(ws + 49152);             // 2 KiB (per-16-row diag mins)
    float* diag10 = (float*)(ws + 65536);        // 32 KiB
    int* Q = (int*)(ws + (1u << 20));            // 1 MiB (i8 frags of 30*F)

    hipMemsetAsync(ws, 0, 8192, stream);         // cnt + acc + S + counters + flags
    k_fused<<<GRID, TPB, 0, stream>>>(F, tgt, diag10, Q, S, cnt, PS, Dpart, acc, bar1, bar2,
                                      flagv, out);
}

// Round 7
// 82.124 us; speedup vs baseline: 2.8333x; 1.0739x over previous
//
#include <hip/hip_runtime.h>

#define N 8192
#define KD 128
#define NCLS 10
#define GRID 512
#define TPB 256

typedef __attribute__((ext_vector_type(4))) int intx4;

// i8 fragment layout (K=64 per MFMA, two ks halves per K=128 row):
//   byte addr = idx16*2048 + ks*1024 + quad*256 + l16*16 + j   (k = ks*64+quad*16+j)
// Q holds rn(30*F) as i8; logit = (qa . qb) / 90.
//
// Coherence (r5/r6): NO __threadfence (agent fences = whole-L2 wb/inv x 512
// leaders ~= 100us, r4). Cross-phase producers use RELAXED AGENT atomic stores
// (write-through to MALL); consumers cache-read never-cached lines (Q/diag10/
// Dpart) or RELAXED AGENT loads (PS/S/cnt).
// Barrier (r7): r6 still funneled 512 fetch_adds into ONE MALL line; same-line
// RMWs serialize (~30ns each ~= 15us/barrier). Two-level tree: 64 group
// counters (8 blocks each, own lines) -> root line -> 8 spread release flags.
// Serialized RMW chain: 8 + 64 per barrier ~= 2us. One counter set serves both
// barriers (group 0->8 then 8->16; root 0->64 then 64->128).

__device__ __forceinline__ float slabmin(const int* __restrict__ Dpart, int slab) {
    float a = fminf(__int_as_float(Dpart[slab * 4 + 0]), __int_as_float(Dpart[slab * 4 + 1]));
    float b = fminf(__int_as_float(Dpart[slab * 4 + 2]), __int_as_float(Dpart[slab * 4 + 3]));
    return fminf(a, b);
}

__device__ __forceinline__ void st_agent(int* p, int v) {
    __hip_atomic_store(p, v, __ATOMIC_RELAXED, __HIP_MEMORY_SCOPE_AGENT);
}
__device__ __forceinline__ void st_agent_f(float* p, float v) {
    __hip_atomic_store(p, v, __ATOMIC_RELAXED, __HIP_MEMORY_SCOPE_AGENT);
}
__device__ __forceinline__ float ld_agent_f(const float* p) {
    return __hip_atomic_load(p, __ATOMIC_RELAXED, __HIP_MEMORY_SCOPE_AGENT);
}
__device__ __forceinline__ int ld_agent(const int* p) {
    return __hip_atomic_load(p, __ATOMIC_RELAXED, __HIP_MEMORY_SCOPE_AGENT);
}
__device__ __forceinline__ int fadd_agent(int* p) {
    return __hip_atomic_fetch_add(p, 1, __ATOMIC_RELAXED, __HIP_MEMORY_SCOPE_AGENT);
}

__device__ __forceinline__ void release_flags(int* flagv, int epoch) {
#pragma unroll
    for (int i = 0; i < 8; ++i) st_agent(&flagv[i * 32], epoch);
}
__device__ __forceinline__ void wait_flag(const int* flagv, int b, int epoch) {
    while (ld_agent(&flagv[(b & 7) * 32]) < epoch) __builtin_amdgcn_s_sleep(2);
}
// Tree arrival. thr_grp: group-counter value of the LAST arriver this phase;
// thr_root: root value of the last group this phase. Caller drained vmcnt.
__device__ __forceinline__ void arrive_tree(int* grp, int* root, int* flagv, int b, int thr_grp,
                                            int thr_root, int epoch) {
    if (fadd_agent(&grp[(b >> 3) * 32]) == thr_grp)
        if (fadd_agent(root) == thr_root) release_flags(flagv, epoch);
}

__global__ __launch_bounds__(TPB, 2) void k_fused(const float* __restrict__ F,
                                                  const int* __restrict__ tgt,
                                                  float* __restrict__ diag10,
                                                  int* __restrict__ Q,
                                                  float* __restrict__ S,
                                                  int* __restrict__ cnt,
                                                  float* __restrict__ PS,
                                                  int* __restrict__ Dpart,
                                                  float* __restrict__ accg,
                                                  int* __restrict__ grp,
                                                  int* __restrict__ root,
                                                  int* __restrict__ flagv,
                                                  float* __restrict__ out) {
    const unsigned char* Qb = (const unsigned char*)Q;
    int b = blockIdx.x;
    int t = threadIdx.x;

    __shared__ int bmin;
    __shared__ union {
        struct { int lh[NCLS]; float red[2][NCLS][KD]; } cls;          // phase 1b
        struct { float Ss[NCLS * KD]; int cs[NCLS]; float wsum[4]; } fin; // phase 3
    } sh;

    // ================= Phase 1a: i8 convert, 16 rows per block =================
    {
        int row0 = b * 16;
        if (t == 0) bmin = 0x7f7fffff;       // +3.4e38 bits
        __syncthreads();
        if (t < 16) st_agent_f(&PS[row0 + t], 0.f);
        int col4 = t & 31;   // which float4 of the row (k = col4*4)
        int rg = t >> 5;     // 0..7
#pragma unroll
        for (int sw = 0; sw < 2; ++sw) {
            int row = row0 + sw * 8 + rg;
            float4 v = *(const float4*)(F + (size_t)row * KD + col4 * 4);
            float sq = v.x * v.x + v.y * v.y + v.z * v.z + v.w * v.w;
#pragma unroll
            for (int off = 16; off >= 1; off >>= 1) sq += __shfl_xor(sq, off);
            if (col4 == 0) {
                float dg = 10.f * sq;
                st_agent_f(&diag10[row], dg);
                atomicMin(&bmin, __float_as_int(dg));   // LDS atomic, 16/block
            }
            // i8 quantize: q = rn(30*clamp(v, +-4.2))
            int q0 = __float2int_rn(30.f * fminf(fmaxf(v.x, -4.2f), 4.2f));
            int q1 = __float2int_rn(30.f * fminf(fmaxf(v.y, -4.2f), 4.2f));
            int q2 = __float2int_rn(30.f * fminf(fmaxf(v.z, -4.2f), 4.2f));
            int q3 = __float2int_rn(30.f * fminf(fmaxf(v.w, -4.2f), 4.2f));
            int dq = (q0 & 255) | ((q1 & 255) << 8) | ((q2 & 255) << 16) | ((q3 & 255) << 24);
            int idx = (row >> 4) * 512 + (col4 >> 4) * 256 + ((col4 >> 2) & 3) * 64 +
                      (row & 15) * 4 + (col4 & 3);
            st_agent(&Q[idx], dq);
        }
        __syncthreads();   // all waves' Q/PS/diag10 stores drained (waitcnt before s_barrier)
        if (t == 0) {
            st_agent(&Dpart[b], bmin);
            asm volatile("s_waitcnt vmcnt(0)" ::: "memory");
            arrive_tree(grp, root, flagv, b, 7, 63, 1);   // barrier-1 ARRIVAL (early)
        }
    }

    // ====== Phase 1b: class sums (blocks 0..127) — overlapped with b1 spin =====
    if (b < 128) {
        int row0 = b * 64;
        int k = t & 127, h = t >> 7;
        if (t < NCLS) sh.cls.lh[t] = 0;
        __syncthreads();
        if (t < 64) atomicAdd(&sh.cls.lh[tgt[row0 + t]], 1);
        float local[NCLS];
#pragma unroll
        for (int c = 0; c < NCLS; ++c) local[c] = 0.f;
        for (int ii = 0; ii < 32; ++ii) {
            int row = row0 + h * 32 + ii;
            float v = F[(size_t)row * KD + k];
            int c = tgt[row];
#pragma unroll
            for (int cc = 0; cc < NCLS; ++cc) local[cc] += (cc == c) ? v : 0.f;
        }
#pragma unroll
        for (int cc = 0; cc < NCLS; ++cc) sh.cls.red[h][cc][k] = local[cc];
        __syncthreads();
        if (h == 0) {
#pragma unroll
            for (int cc = 0; cc < NCLS; ++cc)
                atomicAdd(&S[cc * KD + k], sh.cls.red[0][cc][k] + sh.cls.red[1][cc][k]);
            if (t < NCLS) atomicAdd(&cnt[t], sh.cls.lh[t]);
        }
    }

    // barrier-1 WAIT (poll spread release flags; counter lines have no readers)
    if (t == 0) wait_flag(flagv, b, 1);
    __syncthreads();

    // ================= Phase 2: symmetric-half i8 MFMA pair sweep ==============
    {
        int bx = b & 127, y = b >> 7;
        int w = t >> 6, lane = t & 63;
        int quad = lane >> 4, l16 = lane & 15;
        int row0 = bx * 64;

        float dmr = slabmin(Dpart, bx);   // row-slab min diag

        // A fragments: af[it][ks] for rows row0 + it*16 + l16
        intx4 af[4][2];
#pragma unroll
        for (int it = 0; it < 4; ++it)
#pragma unroll
            for (int ks = 0; ks < 2; ++ks)
                af[it][ks] =
                    *(const intx4*)(Qb + (size_t)(bx * 4 + it) * 2048 + ks * 1024 + lane * 16);

        bool ext = (y == 0) && (bx < 64) && (w == 0);   // handles the dd=64 tile

        // double-buffered B fragments
        intx4 bufs[2][4][2];
        {   // prologue: load step 0 (dd = y*16 + w)
            int col0 = ((bx + y * 16 + w) & 127) * 64;
            const unsigned char* bp = Qb + (size_t)(col0 >> 4) * 2048 + lane * 16;
#pragma unroll
            for (int tj = 0; tj < 4; ++tj)
#pragma unroll
                for (int ks = 0; ks < 2; ++ks)
                    bufs[0][tj][ks] = *(const intx4*)(bp + tj * 2048 + ks * 1024);
        }

#pragma unroll
        for (int s = 0; s < 4; ++s) {
            // prefetch next tile (step s+1, or the dd=64 extra tile on the last step)
            if (s < 3) {
                int coln = ((bx + y * 16 + (s + 1) * 4 + w) & 127) * 64;
                const unsigned char* bp = Qb + (size_t)(coln >> 4) * 2048 + lane * 16;
#pragma unroll
                for (int tj = 0; tj < 4; ++tj)
#pragma unroll
                    for (int ks = 0; ks < 2; ++ks)
                        bufs[(s + 1) & 1][tj][ks] = *(const intx4*)(bp + tj * 2048 + ks * 1024);
            } else if (ext) {
                int coln = (bx + 64) * 64;
                const unsigned char* bp = Qb + (size_t)(coln >> 4) * 2048 + lane * 16;
#pragma unroll
                for (int tj = 0; tj < 4; ++tj)
#pragma unroll
                    for (int ks = 0; ks < 2; ++ks)
                        bufs[0][tj][ks] = *(const intx4*)(bp + tj * 2048 + ks * 1024);
            }

            int csb = (bx + y * 16 + s * 4 + w) & 127;   // col slab index
            int col0 = csb * 64;
            int thrq = (int)((fminf(dmr, slabmin(Dpart, csb)) - 60.f) * 90.f);

            intx4 acc[4][4];
#pragma unroll
            for (int it = 0; it < 4; ++it)
#pragma unroll
                for (int tj = 0; tj < 4; ++tj)
                    acc[it][tj] = (intx4){0, 0, 0, 0};
#pragma unroll
            for (int ks = 0; ks < 2; ++ks)
#pragma unroll
                for (int it = 0; it < 4; ++it)
#pragma unroll
                    for (int tj = 0; tj < 4; ++tj)
                        acc[it][tj] = __builtin_amdgcn_mfma_i32_16x16x64_i8(
                            af[it][ks], bufs[s & 1][tj][ks], acc[it][tj], 0, 0, 0);

            int mx = -2147483647;
#pragma unroll
            for (int it = 0; it < 4; ++it)
#pragma unroll
                for (int tj = 0; tj < 4; ++tj) {
                    int a01 = max(acc[it][tj][0], acc[it][tj][1]);
                    int a23 = max(acc[it][tj][2], acc[it][tj][3]);
                    mx = max(mx, max(a01, a23));
                }

            if (__any(mx > thrq)) {
                bool has_diag = (col0 == row0);   // wave-uniform (dd==0)
                // row side: exp(l - M_row) into PS[row] (self excluded on diag tile)
#pragma unroll
                for (int it = 0; it < 4; ++it)
#pragma unroll
                    for (int r = 0; r < 4; ++r) {
                        int grow = row0 + it * 16 + quad * 4 + r;
                        float Mrow = diag10[grow];
                        float rs = 0.f;
#pragma unroll
                        for (int tj = 0; tj < 4; ++tj) {
                            int gcol = col0 + tj * 16 + l16;
                            float lv = (float)acc[it][tj][r] * (1.f / 90.f);
                            float ev = __expf(lv - Mrow);
                            rs += (grow == gcol) ? 0.f : ev;
                        }
                        rs += __shfl_xor(rs, 1, 16);
                        rs += __shfl_xor(rs, 2, 16);
                        rs += __shfl_xor(rs, 4, 16);
                        rs += __shfl_xor(rs, 8, 16);
                        if (l16 == 0) atomicAdd(&PS[grow], rs);
                    }
                // col side (off-diag tiles only): exp(l - M_col) into PS[col]
                if (!has_diag) {
#pragma unroll
                    for (int tj = 0; tj < 4; ++tj) {
                        int gcol = col0 + tj * 16 + l16;
                        float Mcol = diag10[gcol];
                        float cs_ = 0.f;
#pragma unroll
                        for (int it = 0; it < 4; ++it)
#pragma unroll
                            for (int r = 0; r < 4; ++r)
                                cs_ += __expf((float)acc[it][tj][r] * (1.f / 90.f) - Mcol);
                        cs_ += __shfl_xor(cs_, 16);
                        cs_ += __shfl_xor(cs_, 32);
                        if (quad == 0) atomicAdd(&PS[gcol], cs_);
                    }
                }
            }
        }

        // dd=64 extra tile (unordered pair {bx, bx+64}), off-diag semantics
        if (ext) {
            int col0 = (bx + 64) * 64;
            int thrq = (int)((fminf(dmr, slabmin(Dpart, bx + 64)) - 60.f) * 90.f);
            intx4 acc[4][4];
#pragma unroll
            for (int it = 0; it < 4; ++it)
#pragma unroll
                for (int tj = 0; tj < 4; ++tj)
                    acc[it][tj] = (intx4){0, 0, 0, 0};
#pragma unroll
            for (int ks = 0; ks < 2; ++ks)
#pragma unroll
                for (int it = 0; it < 4; ++it)
#pragma unroll
                    for (int tj = 0; tj < 4; ++tj)
                        acc[it][tj] = __builtin_amdgcn_mfma_i32_16x16x64_i8(
                            af[it][ks], bufs[0][tj][ks], acc[it][tj], 0, 0, 0);

            int mx = -2147483647;
#pragma unroll
            for (int it = 0; it < 4; ++it)
#pragma unroll
                for (int tj = 0; tj < 4; ++tj) {
                    int a01 = max(acc[it][tj][0], acc[it][tj][1]);
                    int a23 = max(acc[it][tj][2], acc[it][tj][3]);
                    mx = max(mx, max(a01, a23));
                }
            if (__any(mx > thrq)) {
#pragma unroll
                for (int it = 0; it < 4; ++it)
#pragma unroll
                    for (int r = 0; r < 4; ++r) {
                        int grow = row0 + it * 16 + quad * 4 + r;
                        float Mrow = diag10[grow];
                        float rs = 0.f;
#pragma unroll
                        for (int tj = 0; tj < 4; ++tj) {
                            float lv = (float)acc[it][tj][r] * (1.f / 90.f);
                            rs += __expf(lv - Mrow);
                        }
                        rs += __shfl_xor(rs, 1, 16);
                        rs += __shfl_xor(rs, 2, 16);
                        rs += __shfl_xor(rs, 4, 16);
                        rs += __shfl_xor(rs, 8, 16);
                        if (l16 == 0) atomicAdd(&PS[grow], rs);
                    }
#pragma unroll
                for (int tj = 0; tj < 4; ++tj) {
                    int gcol = col0 + tj * 16 + l16;
                    float Mcol = diag10[gcol];
                    float cs_ = 0.f;
#pragma unroll
                    for (int it = 0; it < 4; ++it)
#pragma unroll
                        for (int r = 0; r < 4; ++r)
                            cs_ += __expf((float)acc[it][tj][r] * (1.f / 90.f) - Mcol);
                    cs_ += __shfl_xor(cs_, 16);
                    cs_ += __shfl_xor(cs_, 32);
                    if (quad == 0) atomicAdd(&PS[gcol], cs_);
                }
            }
        }
    }

    // ===== barrier 2: everyone arrives; only phase-3 blocks (b<128) wait =======
    __syncthreads();   // drains each wave's phase-2 PS atomics
    if (t == 0) {
        asm volatile("s_waitcnt vmcnt(0)" ::: "memory");
        arrive_tree(grp, root, flagv, b, 15, 127, 2);
    }
    if (b >= 128) return;

    // ================= Phase 3: posdot + log-term + reduce (blocks 0..127) =====
    {
        // Prefetch barrier-independent data while waiting for the release flag.
        int g = t >> 2, q = t & 3;            // 4 lanes per row
        int row = b * 64 + g;
        int c = tgt[row];
        float4 ff[8];
#pragma unroll
        for (int i = 0; i < 8; ++i)
            ff[i] = *(const float4*)(F + (size_t)row * KD + i * 16 + q * 4);
        float M = diag10[row];

        if (t == 0) wait_flag(flagv, b, 2);
        __syncthreads();

        // S/cnt/PS were produced by coherence-point atomics: read with agent-scope
        // (L2-bypass) loads so no stale clean line can be hit.
        for (int i = t; i < NCLS * KD; i += TPB) sh.fin.Ss[i] = ld_agent_f(&S[i]);
        if (t < NCLS) sh.fin.cs[t] = ld_agent(&cnt[t]);
        __syncthreads();

        float dot = 0.f;
#pragma unroll
        for (int i = 0; i < 8; ++i) {
            float4 s = *(const float4*)(sh.fin.Ss + c * KD + i * 16 + q * 4);
            dot += ff[i].x * s.x + ff[i].y * s.y + ff[i].z * s.z + ff[i].w * s.w;
        }
        dot += __shfl_xor(dot, 1, 4);
        dot += __shfl_xor(dot, 2, 4);

        float mlp = 0.f;
        if (q == 0) {
            float pp = 10.f * dot - M;            // sum over positives of logits
            float T = ld_agent_f(&PS[row]);       // surviving shifted exp mass
            float np = (float)(sh.fin.cs[c] - 1);
            mlp = (np < 0.5f) ? 0.f : (pp - np * (M + __logf(T + 1e-20f))) / np;
        }
#pragma unroll
        for (int off = 32; off >= 1; off >>= 1) mlp += __shfl_xor(mlp, off);
        int lane = t & 63, w = t >> 6;
        if (lane == 0) sh.fin.wsum[w] = mlp;
        __syncthreads();
        if (t == 0) {
            atomicAdd(accg, (sh.fin.wsum[0] + sh.fin.wsum[1]) + (sh.fin.wsum[2] + sh.fin.wsum[3]));
            asm volatile("s_waitcnt vmcnt(0)" ::: "memory");   // accg add at MALL before ticket
            int old = atomicAdd(&cnt[12], 1);   // ticket among 128 final blocks
            if (old == 127) {
                float tot = atomicAdd(accg, 0.0f);   // coherent read of total
                double sp = 0.0, sn = 0.0;
                for (int cc = 0; cc < NCLS; ++cc) {
                    double n = (double)sh.fin.cs[cc];
                    sp += n * (n - 1.0);
                    sn += n * ((double)N - n);
                }
                out[0] = (float)(-(0.1 / 0.07) * ((double)tot / (double)N));
                out[1] = (float)(sp / (double)N);
                out[2] = (float)(sn / (double)N);
            }
        }
    }
}

extern "C" void kernel_launch(void* const* d_in, const int* in_sizes, int n_in,
                              void* d_out, int out_size, void* d_ws, size_t ws_size,
                              hipStream_t stream) {
    const float* F = (const float*)d_in[0];
    const int* tgt = (const int*)d_in[1];
    float* out = (float*)d_out;
    char* ws = (char*)d_ws;

    int* cnt = (int*)(ws);                       // 64 B (ticket at cnt[12])
    float* acc = (float*)(ws + 64);              // 4 B
    float* S = (float*)(ws + 128);               // 5120 B -> ends 5248
    int* flagv = (int*)(ws + 6144);              // 8 release-flag copies, 128 B apart
    int* root = (int*)(ws + 7168);               // root arrival counter (own line)
    float* PS = (float*)(ws + 8192);             // 32 KiB (zeroed in phase 1)
    int* grp = (int*)(ws + 40960);               // 64 group counters, 128 B apart (8 KiB)
    int* Dpart = (int*)(ws + 49152);             // 2 KiB (per-16-row diag mins)
    float* diag10 = (float*)(ws + 65536);        // 32 KiB
    int* Q = (int*)(ws + (1u << 20));            // 1 MiB (i8 frags of 30*F)

    hipMemsetAsync(ws, 0, 49152, stream);        // cnt+acc+S+flags+root+PS+groups
    k_fused<<<GRID, TPB, 0, stream>>>(F, tgt, diag10, Q, S, cnt, PS, Dpart, acc, grp, root,
                                      flagv, out);
}

// Round 9
// 80.587 us; speedup vs baseline: 2.8874x; 1.0191x over previous
//
#include <hip/hip_runtime.h>

#define N 8192
#define KD 128
#define NCLS 10
#define GRID 512
#define TPB 256

typedef __attribute__((ext_vector_type(4))) int intx4;

// i8 fragment layout (K=64 per MFMA, two ks halves per K=128 row):
//   byte addr = idx16*2048 + ks*1024 + quad*256 + l16*16 + j   (k = ks*64+quad*16+j)
// Q holds rn(30*F) as i8; logit = (qa . qb) / 90.
//
// Coherence (r5-r7): NO __threadfence (agent fences = whole-L2 wb/inv x 512
// leaders ~= 100us). Cross-phase producers use RELAXED AGENT atomic stores
// (write-through to MALL); consumers cache-read lines first-touched after the
// sync point (dispatch-boundary invalidate makes them coherent) or RELAXED
// AGENT loads for atomically-updated data (PS/S/cnt).
// Sync (r8): global barrier 1 REPLACED by per-slab ready flags (point-to-point:
// consumer starts when ITS 13-20 producer slabs are done; no global last-arriver
// gate). Work rebalanced so barrier-2 arrivals align: 1b->y=2 (3 steps),
// dd=44..47 -> y=0 (5 steps), ext dd=64 -> y=1. Barrier 2 = r7 tree
// (64 group lines -> root -> 8 spread release flags).

__device__ __forceinline__ float slabmin(const int* __restrict__ Dpart, int slab) {
    float a = fminf(__int_as_float(Dpart[slab * 4 + 0]), __int_as_float(Dpart[slab * 4 + 1]));
    float b = fminf(__int_as_float(Dpart[slab * 4 + 2]), __int_as_float(Dpart[slab * 4 + 3]));
    return fminf(a, b);
}

__device__ __forceinline__ void st_agent(int* p, int v) {
    __hip_atomic_store(p, v, __ATOMIC_RELAXED, __HIP_MEMORY_SCOPE_AGENT);
}
__device__ __forceinline__ void st_agent_f(float* p, float v) {
    __hip_atomic_store(p, v, __ATOMIC_RELAXED, __HIP_MEMORY_SCOPE_AGENT);
}
__device__ __forceinline__ float ld_agent_f(const float* p) {
    return __hip_atomic_load(p, __ATOMIC_RELAXED, __HIP_MEMORY_SCOPE_AGENT);
}
__device__ __forceinline__ int ld_agent(const int* p) {
    return __hip_atomic_load(p, __ATOMIC_RELAXED, __HIP_MEMORY_SCOPE_AGENT);
}
__device__ __forceinline__ int fadd_agent(int* p) {
    return __hip_atomic_fetch_add(p, 1, __ATOMIC_RELAXED, __HIP_MEMORY_SCOPE_AGENT);
}

__device__ __forceinline__ void release_flags(int* flagv, int epoch) {
#pragma unroll
    for (int i = 0; i < 8; ++i) st_agent(&flagv[i * 32], epoch);
}
__device__ __forceinline__ void wait_flag(const int* flagv, int b, int epoch) {
    while (ld_agent(&flagv[(b & 7) * 32]) < epoch) __builtin_amdgcn_s_sleep(2);
}
// Barrier-2 tree arrival (thr_grp/thr_root = value seen by the LAST arriver).
__device__ __forceinline__ void arrive_tree(int* grp, int* root, int* flagv, int b, int thr_grp,
                                            int thr_root, int epoch) {
    if (fadd_agent(&grp[(b >> 3) * 32]) == thr_grp)
        if (fadd_agent(root) == thr_root) release_flags(flagv, epoch);
}

__global__ __launch_bounds__(TPB, 2) void k_fused(const float* __restrict__ F,
                                                  const int* __restrict__ tgt,
                                                  float* __restrict__ diag10,
                                                  int* __restrict__ Q,
                                                  float* __restrict__ S,
                                                  int* __restrict__ cnt,
                                                  float* __restrict__ PS,
                                                  int* __restrict__ Dpart,
                                                  float* __restrict__ accg,
                                                  int* __restrict__ grp,
                                                  int* __restrict__ root,
                                                  int* __restrict__ flagv,
                                                  int* __restrict__ slabc,
                                                  int* __restrict__ slabf,
                                                  float* __restrict__ out) {
    const unsigned char* Qb = (const unsigned char*)Q;
    int b = blockIdx.x;
    int t = threadIdx.x;
    int bx = b & 127, y = b >> 7;

    __shared__ int bmin;
    __shared__ union {
        struct { int lh[NCLS]; float red[2][NCLS][KD]; } cls;          // phase 1b (y=2)
        struct { float Ss[NCLS * KD]; int cs[NCLS]; float wsum[4]; } fin; // phase 3 (y=0)
    } sh;

    // ================= Phase 1a: i8 convert, 16 rows per block =================
    {
        int row0 = b * 16;
        if (t == 0) bmin = 0x7f7fffff;       // +3.4e38 bits
        __syncthreads();
        if (t < 16) st_agent_f(&PS[row0 + t], 0.f);
        int col4 = t & 31;   // which float4 of the row (k = col4*4)
        int rg = t >> 5;     // 0..7
#pragma unroll
        for (int sw = 0; sw < 2; ++sw) {
            int row = row0 + sw * 8 + rg;
            float4 v = *(const float4*)(F + (size_t)row * KD + col4 * 4);
            float sq = v.x * v.x + v.y * v.y + v.z * v.z + v.w * v.w;
#pragma unroll
            for (int off = 16; off >= 1; off >>= 1) sq += __shfl_xor(sq, off);
            if (col4 == 0) {
                float dg = 10.f * sq;
                st_agent_f(&diag10[row], dg);
                atomicMin(&bmin, __float_as_int(dg));   // LDS atomic, 16/block
            }
            // i8 quantize: q = rn(30*clamp(v, +-4.2))
            int q0 = __float2int_rn(30.f * fminf(fmaxf(v.x, -4.2f), 4.2f));
            int q1 = __float2int_rn(30.f * fminf(fmaxf(v.y, -4.2f), 4.2f));
            int q2 = __float2int_rn(30.f * fminf(fmaxf(v.z, -4.2f), 4.2f));
            int q3 = __float2int_rn(30.f * fminf(fmaxf(v.w, -4.2f), 4.2f));
            int dq = (q0 & 255) | ((q1 & 255) << 8) | ((q2 & 255) << 16) | ((q3 & 255) << 24);
            int idx = (row >> 4) * 512 + (col4 >> 4) * 256 + ((col4 >> 2) & 3) * 64 +
                      (row & 15) * 4 + (col4 & 3);
            st_agent(&Q[idx], dq);
        }
        __syncthreads();   // every wave drains vmcnt before s_barrier -> all stores at MALL
        if (t == 0) {
            st_agent(&Dpart[b], bmin);
            asm volatile("s_waitcnt vmcnt(0)" ::: "memory");
            // per-slab readiness: 4th chunk-producer of slab b>>2 sets the slab flag
            if (fadd_agent(&slabc[(b >> 2) * 32]) == 3) st_agent(&slabf[(b >> 2) * 32], 1);
        }
    }

    // ====== Phase 1b: class sums (y=2 blocks: 256..383, 64 rows each) ==========
    if (y == 2) {
        int row0 = bx * 64;
        int k = t & 127, h = t >> 7;
        if (t < NCLS) sh.cls.lh[t] = 0;
        __syncthreads();
        if (t < 64) atomicAdd(&sh.cls.lh[tgt[row0 + t]], 1);
        float local[NCLS];
#pragma unroll
        for (int c = 0; c < NCLS; ++c) local[c] = 0.f;
        for (int ii = 0; ii < 32; ++ii) {
            int row = row0 + h * 32 + ii;
            float v = F[(size_t)row * KD + k];
            int c = tgt[row];
#pragma unroll
            for (int cc = 0; cc < NCLS; ++cc) local[cc] += (cc == c) ? v : 0.f;
        }
#pragma unroll
        for (int cc = 0; cc < NCLS; ++cc) sh.cls.red[h][cc][k] = local[cc];
        __syncthreads();
        if (h == 0) {
#pragma unroll
            for (int cc = 0; cc < NCLS; ++cc)
                atomicAdd(&S[cc * KD + k], sh.cls.red[0][cc][k] + sh.cls.red[1][cc][k]);
            if (t < NCLS) atomicAdd(&cnt[t], sh.cls.lh[t]);
        }
    }

    // ===== wait for the 13-20 slabs THIS block consumes (parallel per-lane poll)
    {
        int dd = -1;
        if (y == 0) {
            if (t < 16) dd = t;                 // dd 0..15 (incl. A slab + diag)
            else if (t < 20) dd = t + 28;       // dd 44..47 (the rebalanced steps)
        } else if (y == 1) {
            if (t < 16) dd = 16 + t;            // dd 16..31
            else if (t == 16) dd = 0;           // A slab
            else if (t == 17 && bx < 64) dd = 64;   // ext slab
        } else if (y == 2) {
            if (t < 12) dd = 32 + t;            // dd 32..43
            else if (t == 12) dd = 0;
        } else {
            if (t < 16) dd = 48 + t;            // dd 48..63
            else if (t == 16) dd = 0;
        }
        if (dd >= 0) {
            int s = (bx + dd) & 127;
            while (!ld_agent(&slabf[s * 32])) __builtin_amdgcn_s_sleep(2);
        }
        __syncthreads();
    }

    // ================= Phase 2: symmetric-half i8 MFMA pair sweep ==============
    {
        int w = t >> 6, lane = t & 63;
        int quad = lane >> 4, l16 = lane & 15;
        int row0 = bx * 64;
        int nst = (y == 0) ? 5 : ((y == 2) ? 3 : 4);
        bool ext = (y == 1) && (bx < 64) && (w == 0);   // dd=64 tile

        float dmr = slabmin(Dpart, bx);   // row-slab min diag

        // A fragments: af[it][ks] for rows row0 + it*16 + l16
        intx4 af[4][2];
#pragma unroll
        for (int it = 0; it < 4; ++it)
#pragma unroll
            for (int ks = 0; ks < 2; ++ks)
                af[it][ks] =
                    *(const intx4*)(Qb + (size_t)(bx * 4 + it) * 2048 + ks * 1024 + lane * 16);

        // double-buffered B fragments
        intx4 bufs[2][4][2];
        {   // prologue: load step 0 (dd = y*16 + w)
            int col0 = ((bx + y * 16 + w) & 127) * 64;
            const unsigned char* bp = Qb + (size_t)(col0 >> 4) * 2048 + lane * 16;
#pragma unroll
            for (int tj = 0; tj < 4; ++tj)
#pragma unroll
                for (int ks = 0; ks < 2; ++ks)
                    bufs[0][tj][ks] = *(const intx4*)(bp + tj * 2048 + ks * 1024);
        }

#pragma unroll
        for (int s = 0; s < 5; ++s) {
            if (s < nst) {
                // prefetch next step's slab (or the ext tile on the last step)
                if (s + 1 < nst) {
                    int ddn = (s + 1 < 4) ? (y * 16 + (s + 1) * 4 + w) : (44 + w);
                    int coln = ((bx + ddn) & 127) * 64;
                    const unsigned char* bp = Qb + (size_t)(coln >> 4) * 2048 + lane * 16;
#pragma unroll
                    for (int tj = 0; tj < 4; ++tj)
#pragma unroll
                        for (int ks = 0; ks < 2; ++ks)
                            bufs[(s + 1) & 1][tj][ks] = *(const intx4*)(bp + tj * 2048 + ks * 1024);
                } else if (ext) {
                    int coln = (bx + 64) * 64;
                    const unsigned char* bp = Qb + (size_t)(coln >> 4) * 2048 + lane * 16;
#pragma unroll
                    for (int tj = 0; tj < 4; ++tj)
#pragma unroll
                        for (int ks = 0; ks < 2; ++ks)
                            bufs[0][tj][ks] = *(const intx4*)(bp + tj * 2048 + ks * 1024);
                }

                int dd = (s < 4) ? (y * 16 + s * 4 + w) : (44 + w);
                int csb = (bx + dd) & 127;   // col slab index
                int col0 = csb * 64;
                int thrq = (int)((fminf(dmr, slabmin(Dpart, csb)) - 60.f) * 90.f);

                intx4 acc[4][4];
#pragma unroll
                for (int it = 0; it < 4; ++it)
#pragma unroll
                    for (int tj = 0; tj < 4; ++tj)
                        acc[it][tj] = (intx4){0, 0, 0, 0};
#pragma unroll
                for (int ks = 0; ks < 2; ++ks)
#pragma unroll
                    for (int it = 0; it < 4; ++it)
#pragma unroll
                        for (int tj = 0; tj < 4; ++tj)
                            acc[it][tj] = __builtin_amdgcn_mfma_i32_16x16x64_i8(
                                af[it][ks], bufs[s & 1][tj][ks], acc[it][tj], 0, 0, 0);

                int mx = -2147483647;
#pragma unroll
                for (int it = 0; it < 4; ++it)
#pragma unroll
                    for (int tj = 0; tj < 4; ++tj) {
                        int a01 = max(acc[it][tj][0], acc[it][tj][1]);
                        int a23 = max(acc[it][tj][2], acc[it][tj][3]);
                        mx = max(mx, max(a01, a23));
                    }

                if (__any(mx > thrq)) {
                    bool has_diag = (col0 == row0);   // wave-uniform (dd==0)
                    // row side: exp(l - M_row) into PS[row] (self excluded on diag)
#pragma unroll
                    for (int it = 0; it < 4; ++it)
#pragma unroll
                        for (int r = 0; r < 4; ++r) {
                            int grow = row0 + it * 16 + quad * 4 + r;
                            float Mrow = diag10[grow];
                            float rs = 0.f;
#pragma unroll
                            for (int tj = 0; tj < 4; ++tj) {
                                int gcol = col0 + tj * 16 + l16;
                                float lv = (float)acc[it][tj][r] * (1.f / 90.f);
                                float ev = __expf(lv - Mrow);
                                rs += (grow == gcol) ? 0.f : ev;
                            }
                            rs += __shfl_xor(rs, 1, 16);
                            rs += __shfl_xor(rs, 2, 16);
                            rs += __shfl_xor(rs, 4, 16);
                            rs += __shfl_xor(rs, 8, 16);
                            if (l16 == 0) atomicAdd(&PS[grow], rs);
                        }
                    // col side (off-diag tiles only): exp(l - M_col) into PS[col]
                    if (!has_diag) {
#pragma unroll
                        for (int tj = 0; tj < 4; ++tj) {
                            int gcol = col0 + tj * 16 + l16;
                            float Mcol = diag10[gcol];
                            float cs_ = 0.f;
#pragma unroll
                            for (int it = 0; it < 4; ++it)
#pragma unroll
                                for (int r = 0; r < 4; ++r)
                                    cs_ += __expf((float)acc[it][tj][r] * (1.f / 90.f) - Mcol);
                            cs_ += __shfl_xor(cs_, 16);
                            cs_ += __shfl_xor(cs_, 32);
                            if (quad == 0) atomicAdd(&PS[gcol], cs_);
                        }
                    }
                }
            }
        }

        // dd=64 extra tile (unordered pair {bx, bx+64}), off-diag semantics (y=1)
        if (ext) {
            int col0 = (bx + 64) * 64;
            int thrq = (int)((fminf(dmr, slabmin(Dpart, bx + 64)) - 60.f) * 90.f);
            intx4 acc[4][4];
#pragma unroll
            for (int it = 0; it < 4; ++it)
#pragma unroll
                for (int tj = 0; tj < 4; ++tj)
                    acc[it][tj] = (intx4){0, 0, 0, 0};
#pragma unroll
            for (int ks = 0; ks < 2; ++ks)
#pragma unroll
                for (int it = 0; it < 4; ++it)
#pragma unroll
                    for (int tj = 0; tj < 4; ++tj)
                        acc[it][tj] = __builtin_amdgcn_mfma_i32_16x16x64_i8(
                            af[it][ks], bufs[0][tj][ks], acc[it][tj], 0, 0, 0);

            int mx = -2147483647;
#pragma unroll
            for (int it = 0; it < 4; ++it)
#pragma unroll
                for (int tj = 0; tj < 4; ++tj) {
                    int a01 = max(acc[it][tj][0], acc[it][tj][1]);
                    int a23 = max(acc[it][tj][2], acc[it][tj][3]);
                    mx = max(mx, max(a01, a23));
                }
            if (__any(mx > thrq)) {
#pragma unroll
                for (int it = 0; it < 4; ++it)
#pragma unroll
                    for (int r = 0; r < 4; ++r) {
                        int grow = row0 + it * 16 + quad * 4 + r;
                        float Mrow = diag10[grow];
                        float rs = 0.f;
#pragma unroll
                        for (int tj = 0; tj < 4; ++tj) {
                            float lv = (float)acc[it][tj][r] * (1.f / 90.f);
                            rs += __expf(lv - Mrow);
                        }
                        rs += __shfl_xor(rs, 1, 16);
                        rs += __shfl_xor(rs, 2, 16);
                        rs += __shfl_xor(rs, 4, 16);
                        rs += __shfl_xor(rs, 8, 16);
                        if (l16 == 0) atomicAdd(&PS[grow], rs);
                    }
#pragma unroll
                for (int tj = 0; tj < 4; ++tj) {
                    int gcol = col0 + tj * 16 + l16;
                    float Mcol = diag10[gcol];
                    float cs_ = 0.f;
#pragma unroll
                    for (int it = 0; it < 4; ++it)
#pragma unroll
                        for (int r = 0; r < 4; ++r)
                            cs_ += __expf((float)acc[it][tj][r] * (1.f / 90.f) - Mcol);
                    cs_ += __shfl_xor(cs_, 16);
                    cs_ += __shfl_xor(cs_, 32);
                    if (quad == 0) atomicAdd(&PS[gcol], cs_);
                }
            }
        }
    }

    // ===== barrier 2: everyone arrives; only phase-3 blocks (y=0) wait =========
    __syncthreads();   // drains each wave's phase-2 PS atomics (and y=2's S/cnt)
    if (t == 0) {
        asm volatile("s_waitcnt vmcnt(0)" ::: "memory");
        arrive_tree(grp, root, flagv, b, 7, 63, 1);
    }
    if (b >= 128) return;

    // ================= Phase 3: posdot + log-term + reduce (blocks 0..127) =====
    {
        // Prefetch barrier-independent data while waiting for the release flag.
        int g = t >> 2, q = t & 3;            // 4 lanes per row
        int row = b * 64 + g;
        int c = tgt[row];
        float4 ff[8];
#pragma unroll
        for (int i = 0; i < 8; ++i)
            ff[i] = *(const float4*)(F + (size_t)row * KD + i * 16 + q * 4);
        float M = diag10[row];

        if (t == 0) wait_flag(flagv, b, 1);
        __syncthreads();

        // S/cnt/PS were produced by coherence-point atomics: read with agent-scope
        // (cache-bypass) loads so no stale clean line can be hit.
        for (int i = t; i < NCLS * KD; i += TPB) sh.fin.Ss[i] = ld_agent_f(&S[i]);
        if (t < NCLS) sh.fin.cs[t] = ld_agent(&cnt[t]);
        __syncthreads();

        float dot = 0.f;
#pragma unroll
        for (int i = 0; i < 8; ++i) {
            float4 s = *(const float4*)(sh.fin.Ss + c * KD + i * 16 + q * 4);
            dot += ff[i].x * s.x + ff[i].y * s.y + ff[i].z * s.z + ff[i].w * s.w;
        }
        dot += __shfl_xor(dot, 1, 4);
        dot += __shfl_xor(dot, 2, 4);

        float mlp = 0.f;
        if (q == 0) {
            float pp = 10.f * dot - M;            // sum over positives of logits
            float T = ld_agent_f(&PS[row]);       // surviving shifted exp mass
            float np = (float)(sh.fin.cs[c] - 1);
            mlp = (np < 0.5f) ? 0.f : (pp - np * (M + __logf(T + 1e-20f))) / np;
        }
#pragma unroll
        for (int off = 32; off >= 1; off >>= 1) mlp += __shfl_xor(mlp, off);
        int lane = t & 63, w = t >> 6;
        if (lane == 0) sh.fin.wsum[w] = mlp;
        __syncthreads();
        if (t == 0) {
            atomicAdd(accg, (sh.fin.wsum[0] + sh.fin.wsum[1]) + (sh.fin.wsum[2] + sh.fin.wsum[3]));
            asm volatile("s_waitcnt vmcnt(0)" ::: "memory");   // accg add at MALL before ticket
            int old = atomicAdd(&cnt[12], 1);   // ticket among 128 final blocks
            if (old == 127) {
                float tot = atomicAdd(accg, 0.0f);   // coherent read of total
                double sp = 0.0, sn = 0.0;
                for (int cc = 0; cc < NCLS; ++cc) {
                    double n = (double)sh.fin.cs[cc];
                    sp += n * (n - 1.0);
                    sn += n * ((double)N - n);
                }
                out[0] = (float)(-(0.1 / 0.07) * ((double)tot / (double)N));
                out[1] = (float)(sp / (double)N);
                out[2] = (float)(sn / (double)N);
            }
        }
    }
}

extern "C" void kernel_launch(void* const* d_in, const int* in_sizes, int n_in,
                              void* d_out, int out_size, void* d_ws, size_t ws_size,
                              hipStream_t stream) {
    const float* F = (const float*)d_in[0];
    const int* tgt = (const int*)d_in[1];
    float* out = (float*)d_out;
    char* ws = (char*)d_ws;

    int* cnt = (int*)(ws);                       // 64 B (ticket at cnt[12])
    float* acc = (float*)(ws + 64);              // 4 B
    float* S = (float*)(ws + 128);               // 5120 B -> ends 5248
    int* flagv = (int*)(ws + 6144);              // 8 release-flag copies, 128 B apart
    int* root = (int*)(ws + 7168);               // barrier-2 root counter (own line)
    float* PS = (float*)(ws + 8192);             // 32 KiB (zeroed in phase 1)
    int* grp = (int*)(ws + 40960);               // 64 group counters, 128 B apart (8 KiB)
    int* Dpart = (int*)(ws + 49152);             // 2 KiB (per-16-row diag mins)
    float* diag10 = (float*)(ws + 65536);        // 32 KiB
    int* slabc = (int*)(ws + 131072);            // 128 slab arrival ctrs, 128 B apart (16 KiB)
    int* slabf = (int*)(ws + 147456);            // 128 slab ready flags, 128 B apart (16 KiB)
    int* Q = (int*)(ws + (1u << 20));            // 1 MiB (i8 frags of 30*F)

    hipMemsetAsync(ws, 0, 163840, stream);       // cnt+acc+S+flags+root+PS+grp+slabc+slabf
    k_fused<<<GRID, TPB, 0, stream>>>(F, tgt, diag10, Q, S, cnt, PS, Dpart, acc, grp, root,
                                      flagv, slabc, slabf, out);
}

// Round 10
// 79.899 us; speedup vs baseline: 2.9122x; 1.0086x over previous
//
#include <hip/hip_runtime.h>

#define N 8192
#define KD 128
#define NCLS 10
#define GRID 512
#define TPB 256

typedef __attribute__((ext_vector_type(4))) int intx4;

// i8 fragment layout (K=64 per MFMA, two ks halves per K=128 row):
//   byte addr = idx16*2048 + ks*1024 + quad*256 + l16*16 + j   (k = ks*64+quad*16+j)
// Q holds rn(30*F) as i8; logit = (qa . qb) / 90.
//
// Coherence (r5-r7): NO __threadfence (agent fences = whole-L2 wb/inv x 512
// leaders ~= 100us). Cross-phase producers use RELAXED AGENT atomic stores
// (write-through to MALL); consumers cache-read lines first-touched after the
// sync point or RELAXED AGENT loads for atomically-updated data.
// Sync (r8/r9): barrier 1 = per-slab ready flags (point-to-point); barrier 2 =
// tree (64 group lines -> root -> 8 spread release flags).
// r10: the S/cnt class-sum atomics were a hidden SERIAL chain: 1280 RMWs on one
// 64B line (cnt) + 128 RMWs/address (S) serialize at the MALL atomic unit
// (~25us tail that every barrier inherited). Fix: 8-way replicas (S_rep,
// cnt_rep); block bx adds to replica bx&7; phase 3 sums 8 replicas on load.

__device__ __forceinline__ float slabmin(const int* __restrict__ Dpart, int slab) {
    float a = fminf(__int_as_float(Dpart[slab * 4 + 0]), __int_as_float(Dpart[slab * 4 + 1]));
    float b = fminf(__int_as_float(Dpart[slab * 4 + 2]), __int_as_float(Dpart[slab * 4 + 3]));
    return fminf(a, b);
}

__device__ __forceinline__ void st_agent(int* p, int v) {
    __hip_atomic_store(p, v, __ATOMIC_RELAXED, __HIP_MEMORY_SCOPE_AGENT);
}
__device__ __forceinline__ void st_agent_f(float* p, float v) {
    __hip_atomic_store(p, v, __ATOMIC_RELAXED, __HIP_MEMORY_SCOPE_AGENT);
}
__device__ __forceinline__ float ld_agent_f(const float* p) {
    return __hip_atomic_load(p, __ATOMIC_RELAXED, __HIP_MEMORY_SCOPE_AGENT);
}
__device__ __forceinline__ int ld_agent(const int* p) {
    return __hip_atomic_load(p, __ATOMIC_RELAXED, __HIP_MEMORY_SCOPE_AGENT);
}
__device__ __forceinline__ int fadd_agent(int* p) {
    return __hip_atomic_fetch_add(p, 1, __ATOMIC_RELAXED, __HIP_MEMORY_SCOPE_AGENT);
}

__device__ __forceinline__ void release_flags(int* flagv, int epoch) {
#pragma unroll
    for (int i = 0; i < 8; ++i) st_agent(&flagv[i * 32], epoch);
}
__device__ __forceinline__ void wait_flag(const int* flagv, int b, int epoch) {
    while (ld_agent(&flagv[(b & 7) * 32]) < epoch) __builtin_amdgcn_s_sleep(2);
}
// Barrier-2 tree arrival (thr_grp/thr_root = value seen by the LAST arriver).
__device__ __forceinline__ void arrive_tree(int* grp, int* root, int* flagv, int b, int thr_grp,
                                            int thr_root, int epoch) {
    if (fadd_agent(&grp[(b >> 3) * 32]) == thr_grp)
        if (fadd_agent(root) == thr_root) release_flags(flagv, epoch);
}

__global__ __launch_bounds__(TPB, 2) void k_fused(const float* __restrict__ F,
                                                  const int* __restrict__ tgt,
                                                  float* __restrict__ diag10,
                                                  int* __restrict__ Q,
                                                  float* __restrict__ S_rep,
                                                  int* __restrict__ cnt,
                                                  int* __restrict__ cnt_rep,
                                                  float* __restrict__ PS,
                                                  int* __restrict__ Dpart,
                                                  float* __restrict__ accg,
                                                  int* __restrict__ grp,
                                                  int* __restrict__ root,
                                                  int* __restrict__ flagv,
                                                  int* __restrict__ slabc,
                                                  int* __restrict__ slabf,
                                                  float* __restrict__ out) {
    const unsigned char* Qb = (const unsigned char*)Q;
    int b = blockIdx.x;
    int t = threadIdx.x;
    int bx = b & 127, y = b >> 7;

    __shared__ int bmin;
    __shared__ union {
        struct { int lh[NCLS]; float red[2][NCLS][KD]; } cls;          // phase 1b (y=2)
        struct { float Ss[NCLS * KD]; int cs[NCLS]; float wsum[4]; } fin; // phase 3 (y=0)
    } sh;

    // ================= Phase 1a: i8 convert, 16 rows per block =================
    {
        int row0 = b * 16;
        if (t == 0) bmin = 0x7f7fffff;       // +3.4e38 bits
        __syncthreads();
        if (t < 16) st_agent_f(&PS[row0 + t], 0.f);
        int col4 = t & 31;   // which float4 of the row (k = col4*4)
        int rg = t >> 5;     // 0..7
#pragma unroll
        for (int sw = 0; sw < 2; ++sw) {
            int row = row0 + sw * 8 + rg;
            float4 v = *(const float4*)(F + (size_t)row * KD + col4 * 4);
            float sq = v.x * v.x + v.y * v.y + v.z * v.z + v.w * v.w;
#pragma unroll
            for (int off = 16; off >= 1; off >>= 1) sq += __shfl_xor(sq, off);
            if (col4 == 0) {
                float dg = 10.f * sq;
                st_agent_f(&diag10[row], dg);
                atomicMin(&bmin, __float_as_int(dg));   // LDS atomic, 16/block
            }
            // i8 quantize: q = rn(30*clamp(v, +-4.2))
            int q0 = __float2int_rn(30.f * fminf(fmaxf(v.x, -4.2f), 4.2f));
            int q1 = __float2int_rn(30.f * fminf(fmaxf(v.y, -4.2f), 4.2f));
            int q2 = __float2int_rn(30.f * fminf(fmaxf(v.z, -4.2f), 4.2f));
            int q3 = __float2int_rn(30.f * fminf(fmaxf(v.w, -4.2f), 4.2f));
            int dq = (q0 & 255) | ((q1 & 255) << 8) | ((q2 & 255) << 16) | ((q3 & 255) << 24);
            int idx = (row >> 4) * 512 + (col4 >> 4) * 256 + ((col4 >> 2) & 3) * 64 +
                      (row & 15) * 4 + (col4 & 3);
            st_agent(&Q[idx], dq);
        }
        __syncthreads();   // every wave drains vmcnt before s_barrier -> all stores at MALL
        if (t == 0) {
            st_agent(&Dpart[b], bmin);
            asm volatile("s_waitcnt vmcnt(0)" ::: "memory");
            // per-slab readiness: 4th chunk-producer of slab b>>2 sets the slab flag
            if (fadd_agent(&slabc[(b >> 2) * 32]) == 3) st_agent(&slabf[(b >> 2) * 32], 1);
        }
    }

    // ====== Phase 1b: class sums (y=2 blocks: 256..383, 64 rows each) ==========
    if (y == 2) {
        int row0 = bx * 64;
        int k = t & 127, h = t >> 7;
        if (t < NCLS) sh.cls.lh[t] = 0;
        __syncthreads();
        if (t < 64) atomicAdd(&sh.cls.lh[tgt[row0 + t]], 1);
        float local[NCLS];
#pragma unroll
        for (int c = 0; c < NCLS; ++c) local[c] = 0.f;
        for (int ii = 0; ii < 32; ++ii) {
            int row = row0 + h * 32 + ii;
            float v = F[(size_t)row * KD + k];
            int c = tgt[row];
#pragma unroll
            for (int cc = 0; cc < NCLS; ++cc) local[cc] += (cc == c) ? v : 0.f;
        }
#pragma unroll
        for (int cc = 0; cc < NCLS; ++cc) sh.cls.red[h][cc][k] = local[cc];
        __syncthreads();
        if (h == 0) {
            // r10: add into replica bx&7 -> per-address RMW chain 128 -> 16
            float* srep = S_rep + (bx & 7) * (NCLS * KD);
#pragma unroll
            for (int cc = 0; cc < NCLS; ++cc)
                atomicAdd(&srep[cc * KD + k], sh.cls.red[0][cc][k] + sh.cls.red[1][cc][k]);
            if (t < NCLS) atomicAdd(&cnt_rep[(bx & 7) * 32 + t], sh.cls.lh[t]);
        }
    }

    // ===== wait for the 13-20 slabs THIS block consumes (parallel per-lane poll)
    {
        int dd = -1;
        if (y == 0) {
            if (t < 16) dd = t;                 // dd 0..15 (incl. A slab + diag)
            else if (t < 20) dd = t + 28;       // dd 44..47 (the rebalanced steps)
        } else if (y == 1) {
            if (t < 16) dd = 16 + t;            // dd 16..31
            else if (t == 16) dd = 0;           // A slab
            else if (t == 17 && bx < 64) dd = 64;   // ext slab
        } else if (y == 2) {
            if (t < 12) dd = 32 + t;            // dd 32..43
            else if (t == 12) dd = 0;
        } else {
            if (t < 16) dd = 48 + t;            // dd 48..63
            else if (t == 16) dd = 0;
        }
        if (dd >= 0) {
            int s = (bx + dd) & 127;
            while (!ld_agent(&slabf[s * 32])) __builtin_amdgcn_s_sleep(2);
        }
        __syncthreads();
    }

    // ================= Phase 2: symmetric-half i8 MFMA pair sweep ==============
    {
        int w = t >> 6, lane = t & 63;
        int quad = lane >> 4, l16 = lane & 15;
        int row0 = bx * 64;
        int nst = (y == 0) ? 5 : ((y == 2) ? 3 : 4);
        bool ext = (y == 1) && (bx < 64) && (w == 0);   // dd=64 tile

        float dmr = slabmin(Dpart, bx);   // row-slab min diag

        // A fragments: af[it][ks] for rows row0 + it*16 + l16
        intx4 af[4][2];
#pragma unroll
        for (int it = 0; it < 4; ++it)
#pragma unroll
            for (int ks = 0; ks < 2; ++ks)
                af[it][ks] =
                    *(const intx4*)(Qb + (size_t)(bx * 4 + it) * 2048 + ks * 1024 + lane * 16);

        // double-buffered B fragments
        intx4 bufs[2][4][2];
        {   // prologue: load step 0 (dd = y*16 + w)
            int col0 = ((bx + y * 16 + w) & 127) * 64;
            const unsigned char* bp = Qb + (size_t)(col0 >> 4) * 2048 + lane * 16;
#pragma unroll
            for (int tj = 0; tj < 4; ++tj)
#pragma unroll
                for (int ks = 0; ks < 2; ++ks)
                    bufs[0][tj][ks] = *(const intx4*)(bp + tj * 2048 + ks * 1024);
        }

#pragma unroll
        for (int s = 0; s < 5; ++s) {
            if (s < nst) {
                // prefetch next step's slab (or the ext tile on the last step)
                if (s + 1 < nst) {
                    int ddn = (s + 1 < 4) ? (y * 16 + (s + 1) * 4 + w) : (44 + w);
                    int coln = ((bx + ddn) & 127) * 64;
                    const unsigned char* bp = Qb + (size_t)(coln >> 4) * 2048 + lane * 16;
#pragma unroll
                    for (int tj = 0; tj < 4; ++tj)
#pragma unroll
                        for (int ks = 0; ks < 2; ++ks)
                            bufs[(s + 1) & 1][tj][ks] = *(const intx4*)(bp + tj * 2048 + ks * 1024);
                } else if (ext) {
                    int coln = (bx + 64) * 64;
                    const unsigned char* bp = Qb + (size_t)(coln >> 4) * 2048 + lane * 16;
#pragma unroll
                    for (int tj = 0; tj < 4; ++tj)
#pragma unroll
                        for (int ks = 0; ks < 2; ++ks)
                            bufs[0][tj][ks] = *(const intx4*)(bp + tj * 2048 + ks * 1024);
                }

                int dd = (s < 4) ? (y * 16 + s * 4 + w) : (44 + w);
                int csb = (bx + dd) & 127;   // col slab index
                int col0 = csb * 64;
                int thrq = (int)((fminf(dmr, slabmin(Dpart, csb)) - 60.f) * 90.f);

                intx4 acc[4][4];
#pragma unroll
                for (int it = 0; it < 4; ++it)
#pragma unroll
                    for (int tj = 0; tj < 4; ++tj)
                        acc[it][tj] = (intx4){0, 0, 0, 0};
#pragma unroll
                for (int ks = 0; ks < 2; ++ks)
#pragma unroll
                    for (int it = 0; it < 4; ++it)
#pragma unroll
                        for (int tj = 0; tj < 4; ++tj)
                            acc[it][tj] = __builtin_amdgcn_mfma_i32_16x16x64_i8(
                                af[it][ks], bufs[s & 1][tj][ks], acc[it][tj], 0, 0, 0);

                int mx = -2147483647;
#pragma unroll
                for (int it = 0; it < 4; ++it)
#pragma unroll
                    for (int tj = 0; tj < 4; ++tj) {
                        int a01 = max(acc[it][tj][0], acc[it][tj][1]);
                        int a23 = max(acc[it][tj][2], acc[it][tj][3]);
                        mx = max(mx, max(a01, a23));
                    }

                if (__any(mx > thrq)) {
                    bool has_diag = (col0 == row0);   // wave-uniform (dd==0)
                    // row side: exp(l - M_row) into PS[row] (self excluded on diag)
#pragma unroll
                    for (int it = 0; it < 4; ++it)
#pragma unroll
                        for (int r = 0; r < 4; ++r) {
                            int grow = row0 + it * 16 + quad * 4 + r;
                            float Mrow = diag10[grow];
                            float rs = 0.f;
#pragma unroll
                            for (int tj = 0; tj < 4; ++tj) {
                                int gcol = col0 + tj * 16 + l16;
                                float lv = (float)acc[it][tj][r] * (1.f / 90.f);
                                float ev = __expf(lv - Mrow);
                                rs += (grow == gcol) ? 0.f : ev;
                            }
                            rs += __shfl_xor(rs, 1, 16);
                            rs += __shfl_xor(rs, 2, 16);
                            rs += __shfl_xor(rs, 4, 16);
                            rs += __shfl_xor(rs, 8, 16);
                            if (l16 == 0) atomicAdd(&PS[grow], rs);
                        }
                    // col side (off-diag tiles only): exp(l - M_col) into PS[col]
                    if (!has_diag) {
#pragma unroll
                        for (int tj = 0; tj < 4; ++tj) {
                            int gcol = col0 + tj * 16 + l16;
                            float Mcol = diag10[gcol];
                            float cs_ = 0.f;
#pragma unroll
                            for (int it = 0; it < 4; ++it)
#pragma unroll
                                for (int r = 0; r < 4; ++r)
                                    cs_ += __expf((float)acc[it][tj][r] * (1.f / 90.f) - Mcol);
                            cs_ += __shfl_xor(cs_, 16);
                            cs_ += __shfl_xor(cs_, 32);
                            if (quad == 0) atomicAdd(&PS[gcol], cs_);
                        }
                    }
                }
            }
        }

        // dd=64 extra tile (unordered pair {bx, bx+64}), off-diag semantics (y=1)
        if (ext) {
            int col0 = (bx + 64) * 64;
            int thrq = (int)((fminf(dmr, slabmin(Dpart, bx + 64)) - 60.f) * 90.f);
            intx4 acc[4][4];
#pragma unroll
            for (int it = 0; it < 4; ++it)
#pragma unroll
                for (int tj = 0; tj < 4; ++tj)
                    acc[it][tj] = (intx4){0, 0, 0, 0};
#pragma unroll
            for (int ks = 0; ks < 2; ++ks)
#pragma unroll
                for (int it = 0; it < 4; ++it)
#pragma unroll
                    for (int tj = 0; tj < 4; ++tj)
                        acc[it][tj] = __builtin_amdgcn_mfma_i32_16x16x64_i8(
                            af[it][ks], bufs[0][tj][ks], acc[it][tj], 0, 0, 0);

            int mx = -2147483647;
#pragma unroll
            for (int it = 0; it < 4; ++it)
#pragma unroll
                for (int tj = 0; tj < 4; ++tj) {
                    int a01 = max(acc[it][tj][0], acc[it][tj][1]);
                    int a23 = max(acc[it][tj][2], acc[it][tj][3]);
                    mx = max(mx, max(a01, a23));
                }
            if (__any(mx > thrq)) {
#pragma unroll
                for (int it = 0; it < 4; ++it)
#pragma unroll
                    for (int r = 0; r < 4; ++r) {
                        int grow = row0 + it * 16 + quad * 4 + r;
                        float Mrow = diag10[grow];
                        float rs = 0.f;
#pragma unroll
                        for (int tj = 0; tj < 4; ++tj) {
                            float lv = (float)acc[it][tj][r] * (1.f / 90.f);
                            rs += __expf(lv - Mrow);
                        }
                        rs += __shfl_xor(rs, 1, 16);
                        rs += __shfl_xor(rs, 2, 16);
                        rs += __shfl_xor(rs, 4, 16);
                        rs += __shfl_xor(rs, 8, 16);
                        if (l16 == 0) atomicAdd(&PS[grow], rs);
                    }
#pragma unroll
                for (int tj = 0; tj < 4; ++tj) {
                    int gcol = col0 + tj * 16 + l16;
                    float Mcol = diag10[gcol];
                    float cs_ = 0.f;
#pragma unroll
                    for (int it = 0; it < 4; ++it)
#pragma unroll
                        for (int r = 0; r < 4; ++r)
                            cs_ += __expf((float)acc[it][tj][r] * (1.f / 90.f) - Mcol);
                    cs_ += __shfl_xor(cs_, 16);
                    cs_ += __shfl_xor(cs_, 32);
                    if (quad == 0) atomicAdd(&PS[gcol], cs_);
                }
            }
        }
    }

    // ===== barrier 2: everyone arrives; only phase-3 blocks (y=0) wait =========
    __syncthreads();   // drains each wave's phase-2 PS atomics (and y=2's S/cnt)
    if (t == 0) {
        asm volatile("s_waitcnt vmcnt(0)" ::: "memory");
        arrive_tree(grp, root, flagv, b, 7, 63, 1);
    }
    if (b >= 128) return;

    // ================= Phase 3: posdot + log-term + reduce (blocks 0..127) =====
    {
        // Prefetch barrier-independent data while waiting for the release flag.
        int g = t >> 2, q = t & 3;            // 4 lanes per row
        int row = b * 64 + g;
        int c = tgt[row];
        float4 ff[8];
#pragma unroll
        for (int i = 0; i < 8; ++i)
            ff[i] = *(const float4*)(F + (size_t)row * KD + i * 16 + q * 4);
        float M = diag10[row];

        if (t == 0) wait_flag(flagv, b, 1);
        __syncthreads();

        // Sum the 8 S/cnt replicas with agent-scope (cache-bypass) loads.
        for (int i = t; i < NCLS * KD; i += TPB) {
            float sv = 0.f;
#pragma unroll
            for (int r = 0; r < 8; ++r) sv += ld_agent_f(&S_rep[r * (NCLS * KD) + i]);
            sh.fin.Ss[i] = sv;
        }
        if (t < NCLS) {
            int cv = 0;
#pragma unroll
            for (int r = 0; r < 8; ++r) cv += ld_agent(&cnt_rep[r * 32 + t]);
            sh.fin.cs[t] = cv;
        }
        __syncthreads();

        float dot = 0.f;
#pragma unroll
        for (int i = 0; i < 8; ++i) {
            float4 s = *(const float4*)(sh.fin.Ss + c * KD + i * 16 + q * 4);
            dot += ff[i].x * s.x + ff[i].y * s.y + ff[i].z * s.z + ff[i].w * s.w;
        }
        dot += __shfl_xor(dot, 1, 4);
        dot += __shfl_xor(dot, 2, 4);

        float mlp = 0.f;
        if (q == 0) {
            float pp = 10.f * dot - M;            // sum over positives of logits
            float T = ld_agent_f(&PS[row]);       // surviving shifted exp mass
            float np = (float)(sh.fin.cs[c] - 1);
            mlp = (np < 0.5f) ? 0.f : (pp - np * (M + __logf(T + 1e-20f))) / np;
        }
#pragma unroll
        for (int off = 32; off >= 1; off >>= 1) mlp += __shfl_xor(mlp, off);
        int lane = t & 63, w = t >> 6;
        if (lane == 0) sh.fin.wsum[w] = mlp;
        __syncthreads();
        if (t == 0) {
            atomicAdd(accg, (sh.fin.wsum[0] + sh.fin.wsum[1]) + (sh.fin.wsum[2] + sh.fin.wsum[3]));
            asm volatile("s_waitcnt vmcnt(0)" ::: "memory");   // accg add at MALL before ticket
            int old = atomicAdd(&cnt[12], 1);   // ticket among 128 final blocks
            if (old == 127) {
                float tot = atomicAdd(accg, 0.0f);   // coherent read of total
                double sp = 0.0, sn = 0.0;
                for (int cc = 0; cc < NCLS; ++cc) {
                    double n = (double)sh.fin.cs[cc];
                    sp += n * (n - 1.0);
                    sn += n * ((double)N - n);
                }
                out[0] = (float)(-(0.1 / 0.07) * ((double)tot / (double)N));
                out[1] = (float)(sp / (double)N);
                out[2] = (float)(sn / (double)N);
            }
        }
    }
}

extern "C" void kernel_launch(void* const* d_in, const int* in_sizes, int n_in,
                              void* d_out, int out_size, void* d_ws, size_t ws_size,
                              hipStream_t stream) {
    const float* F = (const float*)d_in[0];
    const int* tgt = (const int*)d_in[1];
    float* out = (float*)d_out;
    char* ws = (char*)d_ws;

    int* cnt = (int*)(ws);                       // 64 B (ticket at cnt[12])
    float* acc = (float*)(ws + 64);              // 4 B
    int* flagv = (int*)(ws + 6144);              // 8 release-flag copies, 128 B apart
    int* root = (int*)(ws + 7168);               // barrier-2 root counter (own line)
    float* S_rep = (float*)(ws + 8192);          // 8 replicas x 5120 B = 40 KiB -> 49152
    int* grp = (int*)(ws + 49152);               // 64 group counters, 128 B apart (8 KiB)
    int* slabc = (int*)(ws + 57344);             // 128 slab arrival ctrs, 128 B apart (16 KiB)
    int* slabf = (int*)(ws + 73728);             // 128 slab ready flags, 128 B apart (16 KiB)
    int* cnt_rep = (int*)(ws + 90112);           // 8 replicas x 128 B = 1 KiB
    float* PS = (float*)(ws + 98304);            // 32 KiB (zeroed in phase 1)
    int* Dpart = (int*)(ws + 131072);            // 2 KiB (per-16-row diag mins)
    float* diag10 = (float*)(ws + 163840);       // 32 KiB
    int* Q = (int*)(ws + (1u << 20));            // 1 MiB (i8 frags of 30*F)

    hipMemsetAsync(ws, 0, 98304, stream);        // cnt+acc+flags+root+S_rep+grp+slabc+slabf+cnt_rep
    k_fused<<<GRID, TPB, 0, stream>>>(F, tgt, diag10, Q, S_rep, cnt, cnt_rep, PS, Dpart, acc,
                                      grp, root, flagv, slabc, slabf, out);
}